// Round 4
// baseline (3139.397 us; speedup 1.0000x reference)
//
#include <hip/hip_runtime.h>

#define NB 32
#define NN 8192
#define NC 256
#define NP 32
#define MYFLT_MAX 3.402823466e+38f

__device__ __forceinline__ float b2f(unsigned short u) {
    return __uint_as_float(((unsigned)u) << 16);
}
__device__ __forceinline__ unsigned short f2b(float f) {
    unsigned u = __float_as_uint(f);
    unsigned r = u + 0x7fffu + ((u >> 16) & 1u);
    return (unsigned short)(r >> 16);
}
// dtype-dispatched element load (index in ELEMENTS, loader handles width)
template<bool F32>
__device__ __forceinline__ float LD(const void* __restrict__ p, size_t i) {
    if (F32) return ((const float* __restrict__)p)[i];
    else     return b2f(((const unsigned short* __restrict__)p)[i]);
}
// exact f32, no FMA contraction, reference association ((x*x + y*y) + z*z)
__device__ __forceinline__ float sq3(float x, float y, float z) {
    return __fadd_rn(__fadd_rn(__fmul_rn(x, x), __fmul_rn(y, y)), __fmul_rn(z, z));
}

// ---------------------------------------------------------------- init: zero scale + flag
__global__ void init_kernel(unsigned int* w) {
    w[0] = 0u;   // scale_bits
    w[2] = 0u;   // dtype flag (0 = bf16, >0 = f32)
}

// ---------------------------------------------------------------- dtype probe
// Scan first 786432 ushorts of `data` (in-bounds under BOTH dtypes).
// Even-indexed ushorts are f32 mantissa-low halves under f32-truth ->
// ~1/256 have the bf16 Inf/NaN exponent pattern. Genuine bf16 data
// (finite normals) can never have exp==0xFF. count>0 <=> f32.
__global__ __launch_bounds__(256) void detect_kernel(
        const void* __restrict__ data, unsigned int* __restrict__ flag) {
    const unsigned short* u = (const unsigned short*)data;
    int t = blockIdx.x * 256 + threadIdx.x;       // 65536 threads
    unsigned cnt = 0;
    for (size_t i = (size_t)t * 2; i < 786432; i += 131072)
        if ((u[i] & 0x7F80u) == 0x7F80u) cnt++;
    if (cnt) atomicAdd(flag, cnt);
}

// ---------------------------------------------------------------- FPS
// one block/batch; 1024 threads x 8 points in registers; winner coords
// broadcast through LDS by the owning thread.
template<bool F32>
__global__ __launch_bounds__(1024) void fps_kernel(
        const void* __restrict__ data, const unsigned int* __restrict__ flagp,
        float* __restrict__ centers) {
    __shared__ float rv[16];
    __shared__ int   ri[16];
    __shared__ int   winIdx;
    __shared__ float winPt[4];
    if ((flagp[0] != 0u) != F32) return;          // wrong-dtype variant: exit
    const int b = blockIdx.x, tid = threadIdx.x;
    const size_t base = (size_t)b * 3 * NN;
    const float x0 = LD<F32>(data, base);
    const float y0 = LD<F32>(data, base + NN);
    const float z0 = LD<F32>(data, base + 2 * NN);
    float px[8], py[8], pz[8], mind[8];
#pragma unroll
    for (int j = 0; j < 8; j++) {
        int n = tid + 1024 * j;
        px[j] = LD<F32>(data, base + n);
        py[j] = LD<F32>(data, base + NN + n);
        pz[j] = LD<F32>(data, base + 2 * NN + n);
        mind[j] = sq3(__fsub_rn(px[j], x0), __fsub_rn(py[j], y0), __fsub_rn(pz[j], z0));
    }
    if (tid == 0) {
        centers[(b * NC + 0) * 3 + 0] = x0;
        centers[(b * NC + 0) * 3 + 1] = y0;
        centers[(b * NC + 0) * 3 + 2] = z0;
    }
    for (int i = 1; i < NC; i++) {
        // local argmax, first-index tie-break
        float bv = mind[0]; int bn = tid;
#pragma unroll
        for (int j = 1; j < 8; j++)
            if (mind[j] > bv) { bv = mind[j]; bn = tid + 1024 * j; }
#pragma unroll
        for (int off = 32; off >= 1; off >>= 1) {
            float ov = __shfl_down(bv, off);
            int   on = __shfl_down(bn, off);
            if (ov > bv || (ov == bv && on < bn)) { bv = ov; bn = on; }
        }
        if ((tid & 63) == 0) { rv[tid >> 6] = bv; ri[tid >> 6] = bn; }
        __syncthreads();                           // A
        if (tid == 0) {
            float cv = rv[0]; int cn = ri[0];
#pragma unroll
            for (int w = 1; w < 16; w++)
                if (rv[w] > cv || (rv[w] == cv && ri[w] < cn)) { cv = rv[w]; cn = ri[w]; }
            if ((unsigned)cn >= NN) cn = 0;        // NaN-safety clamp
            winIdx = cn;
        }
        __syncthreads();                           // B
        const int g = winIdx;
        if ((g & 1023) == tid) {                   // owner broadcasts its registers
            int j = g >> 10;
            winPt[0] = px[j]; winPt[1] = py[j]; winPt[2] = pz[j];
        }
        __syncthreads();                           // C
        const float cx = winPt[0], cy = winPt[1], cz = winPt[2];
#pragma unroll
        for (int j = 0; j < 8; j++) {
            float d = sq3(__fsub_rn(px[j], cx), __fsub_rn(py[j], cy), __fsub_rn(pz[j], cz));
            mind[j] = fminf(mind[j], d);
        }
        if (tid == 0) {
            centers[(b * NC + i) * 3 + 0] = cx;
            centers[(b * NC + i) * 3 + 1] = cy;
            centers[(b * NC + i) * 3 + 2] = cz;
        }
    }
}

// ---------------------------------------------------------------- kNN norm pass -> global scale
template<bool F32>
__global__ __launch_bounds__(256) void knn_kernel(
        const void* __restrict__ data, const int* __restrict__ perm,
        const float* __restrict__ centers, const unsigned int* __restrict__ flagp,
        unsigned int* __restrict__ scale_bits) {
    __shared__ float dist[NN];
    __shared__ float rv4[4];
    __shared__ int   ri4[4];
    __shared__ int   winbuf;
    __shared__ int   sel[NP];
    if ((flagp[0] != 0u) != F32) return;
    const int m = blockIdx.x, b = m >> 8, c = m & 255, tid = threadIdx.x;
    const int ci = perm[c];
    const float cx = centers[((size_t)b * NC + ci) * 3 + 0];
    const float cy = centers[((size_t)b * NC + ci) * 3 + 1];
    const float cz = centers[((size_t)b * NC + ci) * 3 + 2];
    const float cn2 = sq3(cx, cy, cz);
    const size_t base = (size_t)b * 3 * NN;

    float bv = MYFLT_MAX; int bn = tid;
#pragma unroll 4
    for (int j = 0; j < 32; j++) {
        int n = tid + 256 * j;
        float x = LD<F32>(data, base + n);
        float y = LD<F32>(data, base + NN + n);
        float z = LD<F32>(data, base + 2 * NN + n);
        float pn2 = sq3(x, y, z);
        float dot = __fadd_rn(__fadd_rn(__fmul_rn(cx, x), __fmul_rn(cy, y)), __fmul_rn(cz, z));
        float d = __fsub_rn(__fadd_rn(cn2, pn2), __fmul_rn(2.0f, dot));
        dist[n] = d;
        if (d < bv) { bv = d; bn = n; }
    }
    for (int r = 0; r < NP; r++) {
        float v = bv; int n = bn;
#pragma unroll
        for (int off = 32; off >= 1; off >>= 1) {
            float ov = __shfl_down(v, off);
            int   on = __shfl_down(n, off);
            if (ov < v || (ov == v && on < n)) { v = ov; n = on; }
        }
        if ((tid & 63) == 0) { rv4[tid >> 6] = v; ri4[tid >> 6] = n; }
        __syncthreads();
        if (tid == 0) {
            float cv = rv4[0]; int cn = ri4[0];
#pragma unroll
            for (int w = 1; w < 4; w++)
                if (rv4[w] < cv || (rv4[w] == cv && ri4[w] < cn)) { cv = rv4[w]; cn = ri4[w]; }
            if ((unsigned)cn >= NN) cn = 0;        // NaN-safety clamp
            winbuf = cn; sel[r] = cn;
        }
        __syncthreads();
        const int g = winbuf;
        if ((g & 255) == tid) {                    // owner removes + rescans its chunk
            dist[g] = MYFLT_MAX;
            bv = MYFLT_MAX; bn = tid;
#pragma unroll 4
            for (int j = 0; j < 32; j++) {
                int nn2 = tid + 256 * j;
                float v2 = dist[nn2];
                if (v2 < bv) { bv = v2; bn = nn2; }
            }
        }
    }
    __syncthreads();
    if (tid < 32) {
        const int g = sel[tid];
        float x = LD<F32>(data, base + g);
        float y = LD<F32>(data, base + NN + g);
        float z = LD<F32>(data, base + 2 * NN + g);
        float sx = x, sy = y, sz = z;
#pragma unroll
        for (int msk = 16; msk >= 1; msk >>= 1) {
            sx += __shfl_xor(sx, msk);
            sy += __shfl_xor(sy, msk);
            sz += __shfl_xor(sz, msk);
        }
        float lx = x - sx / 32.0f, ly = y - sy / 32.0f, lz = z - sz / 32.0f;
        float n2 = sq3(lx, ly, lz);
#pragma unroll
        for (int msk = 16; msk >= 1; msk >>= 1)
            n2 = fmaxf(n2, __shfl_xor(n2, msk));
        if (tid == 0) atomicMax(scale_bits, __float_as_uint(n2));
    }
}

// ---------------------------------------------------------------- scale
__global__ void finalize_kernel(const unsigned int* scale_bits, float* scale_v) {
    scale_v[0] = sqrtf(__uint_as_float(scale_bits[0]));
}

// ---------------------------------------------------------------- fused knn + encoder + decoder
template<bool F32>
__global__ __launch_bounds__(256) void encdec_kernel(
        const void* __restrict__ data,
        const int* __restrict__ perm, const float* __restrict__ centers,
        const float* __restrict__ scale_p, const unsigned int* __restrict__ flagp,
        const void* __restrict__ gridw,
        const void* __restrict__ We1, const void* __restrict__ be1,
        const void* __restrict__ We2, const void* __restrict__ be2,
        const void* __restrict__ Wf1a, const void* __restrict__ bf1a,
        const void* __restrict__ Wf1b, const void* __restrict__ bf1b,
        const void* __restrict__ Wf1c, const void* __restrict__ bf1c,
        const void* __restrict__ Wf2a, const void* __restrict__ bf2a,
        const void* __restrict__ Wf2b, const void* __restrict__ bf2b,
        const void* __restrict__ Wf2c, const void* __restrict__ bf2c,
        void* __restrict__ out) {
    __shared__ float bigA[256 * 36];   // 36.9 KB: dist[8192], then g1 [k][p] stride 36
    __shared__ float bigB[128 * 36];   // 18.4 KB: h1 then g2, [k][p]
    __shared__ float code[256];
    __shared__ float xb[96];
    __shared__ float fb[96];
    __shared__ float gridb[64];
    __shared__ float meansh[4];
    __shared__ float rv4[4];
    __shared__ int   ri4[4];
    __shared__ int   winbuf;
    __shared__ int   sel[NP];
    if ((flagp[0] != 0u) != F32) return;
    // reversed mapping: overlay region (low d_out bytes) is written by the
    // LAST-dispatched blocks -> every block's early reads precede those writes.
    const int m = (NB * NC - 1) - blockIdx.x;
    const int b = m >> 8, c = m & 255, tid = threadIdx.x;
    // ---- early reads of cross-kernel scalars ----
    const float scale = scale_p[0];
    const int ci = perm[c];
    const float cx = centers[((size_t)b * NC + ci) * 3 + 0];
    const float cy = centers[((size_t)b * NC + ci) * 3 + 1];
    const float cz = centers[((size_t)b * NC + ci) * 3 + 2];
    const float cn2 = sq3(cx, cy, cz);
    const size_t base = (size_t)b * 3 * NN;
    if (tid < 64) gridb[tid] = LD<F32>(gridw, tid);

    // ---- recompute kNN selection (dist lives in bigA) ----
    float* dist = bigA;
    float bv = MYFLT_MAX; int bn = tid;
#pragma unroll 4
    for (int j = 0; j < 32; j++) {
        int n = tid + 256 * j;
        float x = LD<F32>(data, base + n);
        float y = LD<F32>(data, base + NN + n);
        float z = LD<F32>(data, base + 2 * NN + n);
        float pn2 = sq3(x, y, z);
        float dot = __fadd_rn(__fadd_rn(__fmul_rn(cx, x), __fmul_rn(cy, y)), __fmul_rn(cz, z));
        float d = __fsub_rn(__fadd_rn(cn2, pn2), __fmul_rn(2.0f, dot));
        dist[n] = d;
        if (d < bv) { bv = d; bn = n; }
    }
    for (int r = 0; r < NP; r++) {
        float v = bv; int n = bn;
#pragma unroll
        for (int off = 32; off >= 1; off >>= 1) {
            float ov = __shfl_down(v, off);
            int   on = __shfl_down(n, off);
            if (ov < v || (ov == v && on < n)) { v = ov; n = on; }
        }
        if ((tid & 63) == 0) { rv4[tid >> 6] = v; ri4[tid >> 6] = n; }
        __syncthreads();
        if (tid == 0) {
            float cv = rv4[0]; int cn = ri4[0];
#pragma unroll
            for (int w = 1; w < 4; w++)
                if (rv4[w] < cv || (rv4[w] == cv && ri4[w] < cn)) { cv = rv4[w]; cn = ri4[w]; }
            if ((unsigned)cn >= NN) cn = 0;        // NaN-safety clamp
            winbuf = cn; sel[r] = cn;
        }
        __syncthreads();
        const int g = winbuf;
        if ((g & 255) == tid) {
            dist[g] = MYFLT_MAX;
            bv = MYFLT_MAX; bn = tid;
#pragma unroll 4
            for (int j = 0; j < 32; j++) {
                int nn2 = tid + 256 * j;
                float v2 = dist[nn2];
                if (v2 < bv) { bv = v2; bn = nn2; }
            }
        }
    }
    __syncthreads();
    // ---- gather, mean, normalized locals ----
    if (tid < 32) {
        const int g = sel[tid];
        float x = LD<F32>(data, base + g);
        float y = LD<F32>(data, base + NN + g);
        float z = LD<F32>(data, base + 2 * NN + g);
        float sx = x, sy = y, sz = z;
#pragma unroll
        for (int msk = 16; msk >= 1; msk >>= 1) {
            sx += __shfl_xor(sx, msk);
            sy += __shfl_xor(sy, msk);
            sz += __shfl_xor(sz, msk);
        }
        float mx = sx / 32.0f, my = sy / 32.0f, mz = sz / 32.0f;
        xb[tid * 3 + 0] = (x - mx) / scale;
        xb[tid * 3 + 1] = (y - my) / scale;
        xb[tid * 3 + 2] = (z - mz) / scale;
        if (tid == 0) { meansh[0] = mx; meansh[1] = my; meansh[2] = mz; }
    }
    __syncthreads();
    // ---- E2: h1[32,128] -> bigB[k][p] ----
    for (int o = tid; o < 4096; o += 256) {
        int p = o >> 7, i = o & 127;
        float v = xb[p * 3 + 0] * LD<F32>(We1, i) + xb[p * 3 + 1] * LD<F32>(We1, 128 + i)
                + xb[p * 3 + 2] * LD<F32>(We1, 256 + i) + LD<F32>(be1, i);
        bigB[i * 36 + p] = fmaxf(v, 0.0f);
    }
    __syncthreads();
    // ---- E3: code[j] = relu(max_p (h1@We2)[p,j] + be2[j]) ----
    {
        float acc[32];
#pragma unroll
        for (int p = 0; p < 32; p++) acc[p] = 0.0f;
        for (int k = 0; k < 128; k++) {
            float w = LD<F32>(We2, k * 256 + tid);
            const float4* hp = (const float4*)&bigB[k * 36];
#pragma unroll
            for (int q = 0; q < 8; q++) {
                float4 h4 = hp[q];
                acc[q * 4 + 0] = fmaf(h4.x, w, acc[q * 4 + 0]);
                acc[q * 4 + 1] = fmaf(h4.y, w, acc[q * 4 + 1]);
                acc[q * 4 + 2] = fmaf(h4.z, w, acc[q * 4 + 2]);
                acc[q * 4 + 3] = fmaf(h4.w, w, acc[q * 4 + 3]);
            }
        }
        float mx = acc[0];
#pragma unroll
        for (int p = 1; p < 32; p++) mx = fmaxf(mx, acc[p]);
        code[tid] = fmaxf(mx + LD<F32>(be2, tid), 0.0f);
    }
    __syncthreads();
    // ---- D1 fold1-a -> bigA ----
    {
        float a0 = 0.f, a1 = 0.f, a2 = 0.f, a3 = 0.f;
        for (int k = 0; k < 256; k += 4) {
            a0 = fmaf(code[k + 0], LD<F32>(Wf1a, (k + 0) * 256 + tid), a0);
            a1 = fmaf(code[k + 1], LD<F32>(Wf1a, (k + 1) * 256 + tid), a1);
            a2 = fmaf(code[k + 2], LD<F32>(Wf1a, (k + 2) * 256 + tid), a2);
            a3 = fmaf(code[k + 3], LD<F32>(Wf1a, (k + 3) * 256 + tid), a3);
        }
        float base1 = ((a0 + a1) + (a2 + a3)) + LD<F32>(bf1a, tid);
        float wu = LD<F32>(Wf1a, 65536 + tid);   // row 256
        float wv = LD<F32>(Wf1a, 65792 + tid);   // row 257
#pragma unroll 8
        for (int p = 0; p < 32; p++) {
            float v = base1 + gridb[2 * p] * wu + gridb[2 * p + 1] * wv;
            bigA[tid * 36 + p] = fmaxf(v, 0.0f);
        }
    }
    __syncthreads();
    // ---- D2 fold1-b: [32,256]@[256,128] relu -> bigB ----
    {
        int j = tid & 127, ph = tid >> 7;
        float acc[16];
#pragma unroll
        for (int q = 0; q < 16; q++) acc[q] = 0.0f;
        for (int k = 0; k < 256; k++) {
            float w = LD<F32>(Wf1b, k * 128 + j);
            const float4* gp = (const float4*)&bigA[k * 36 + ph * 16];
            float4 h0 = gp[0], h1 = gp[1], h2 = gp[2], h3 = gp[3];
            acc[0] = fmaf(h0.x, w, acc[0]);   acc[1] = fmaf(h0.y, w, acc[1]);
            acc[2] = fmaf(h0.z, w, acc[2]);   acc[3] = fmaf(h0.w, w, acc[3]);
            acc[4] = fmaf(h1.x, w, acc[4]);   acc[5] = fmaf(h1.y, w, acc[5]);
            acc[6] = fmaf(h1.z, w, acc[6]);   acc[7] = fmaf(h1.w, w, acc[7]);
            acc[8] = fmaf(h2.x, w, acc[8]);   acc[9] = fmaf(h2.y, w, acc[9]);
            acc[10] = fmaf(h2.z, w, acc[10]); acc[11] = fmaf(h2.w, w, acc[11]);
            acc[12] = fmaf(h3.x, w, acc[12]); acc[13] = fmaf(h3.y, w, acc[13]);
            acc[14] = fmaf(h3.z, w, acc[14]); acc[15] = fmaf(h3.w, w, acc[15]);
        }
        float bb = LD<F32>(bf1b, j);
#pragma unroll
        for (int q = 0; q < 16; q++)
            bigB[j * 36 + ph * 16 + q] = fmaxf(acc[q] + bb, 0.0f);
    }
    __syncthreads();
    // ---- D3 fold1-c -> fb (no relu) ----
    if (tid < 96) {
        int p = tid / 3, e = tid % 3;
        float acc = 0.0f;
        for (int k = 0; k < 128; k++)
            acc = fmaf(bigB[k * 36 + p], LD<F32>(Wf1c, k * 3 + e), acc);
        fb[tid] = acc + LD<F32>(bf1c, e);
    }
    __syncthreads();
    // ---- D4 fold2-a -> bigA ----
    {
        float a0 = 0.f, a1 = 0.f, a2 = 0.f, a3 = 0.f;
        for (int k = 0; k < 256; k += 4) {
            a0 = fmaf(code[k + 0], LD<F32>(Wf2a, (k + 0) * 256 + tid), a0);
            a1 = fmaf(code[k + 1], LD<F32>(Wf2a, (k + 1) * 256 + tid), a1);
            a2 = fmaf(code[k + 2], LD<F32>(Wf2a, (k + 2) * 256 + tid), a2);
            a3 = fmaf(code[k + 3], LD<F32>(Wf2a, (k + 3) * 256 + tid), a3);
        }
        float base2 = ((a0 + a1) + (a2 + a3)) + LD<F32>(bf2a, tid);
        float w0 = LD<F32>(Wf2a, 65536 + tid);   // row 256
        float w1 = LD<F32>(Wf2a, 65792 + tid);   // row 257
        float w2 = LD<F32>(Wf2a, 66048 + tid);   // row 258
#pragma unroll 8
        for (int p = 0; p < 32; p++) {
            float v = base2 + fb[p * 3] * w0 + fb[p * 3 + 1] * w1 + fb[p * 3 + 2] * w2;
            bigA[tid * 36 + p] = fmaxf(v, 0.0f);
        }
    }
    __syncthreads();
    // ---- D5 fold2-b -> bigB ----
    {
        int j = tid & 127, ph = tid >> 7;
        float acc[16];
#pragma unroll
        for (int q = 0; q < 16; q++) acc[q] = 0.0f;
        for (int k = 0; k < 256; k++) {
            float w = LD<F32>(Wf2b, k * 128 + j);
            const float4* gp = (const float4*)&bigA[k * 36 + ph * 16];
            float4 h0 = gp[0], h1 = gp[1], h2 = gp[2], h3 = gp[3];
            acc[0] = fmaf(h0.x, w, acc[0]);   acc[1] = fmaf(h0.y, w, acc[1]);
            acc[2] = fmaf(h0.z, w, acc[2]);   acc[3] = fmaf(h0.w, w, acc[3]);
            acc[4] = fmaf(h1.x, w, acc[4]);   acc[5] = fmaf(h1.y, w, acc[5]);
            acc[6] = fmaf(h1.z, w, acc[6]);   acc[7] = fmaf(h1.w, w, acc[7]);
            acc[8] = fmaf(h2.x, w, acc[8]);   acc[9] = fmaf(h2.y, w, acc[9]);
            acc[10] = fmaf(h2.z, w, acc[10]); acc[11] = fmaf(h2.w, w, acc[11]);
            acc[12] = fmaf(h3.x, w, acc[12]); acc[13] = fmaf(h3.y, w, acc[13]);
            acc[14] = fmaf(h3.z, w, acc[14]); acc[15] = fmaf(h3.w, w, acc[15]);
        }
        float bb = LD<F32>(bf2b, j);
#pragma unroll
        for (int q = 0; q < 16; q++)
            bigB[j * 36 + ph * 16 + q] = fmaxf(acc[q] + bb, 0.0f);
    }
    __syncthreads();
    // ---- D6 fold2-c + epilogue ----
    if (tid < 96) {
        int p = tid / 3, e = tid % 3;
        float acc = 0.0f;
        for (int k = 0; k < 128; k++)
            acc = fmaf(bigB[k * 36 + p], LD<F32>(Wf2c, k * 3 + e), acc);
        float v = (acc + LD<F32>(bf2c, e)) * scale + meansh[e];
        size_t oi = (size_t)m * 96 + tid;
        if (F32) ((float*)out)[oi] = v;
        else     ((unsigned short*)out)[oi] = f2b(v);
    }
}

extern "C" void kernel_launch(void* const* d_in, const int* in_sizes, int n_in,
                              void* d_out, int out_size, void* d_ws, size_t ws_size,
                              hipStream_t stream) {
    const void* data = d_in[0];
    const int* perm  = (const int*)d_in[1];
    const void* grid = d_in[2];
    const void *We1 = d_in[3], *be1 = d_in[4], *We2 = d_in[5], *be2 = d_in[6];
    const void *Wf1a = d_in[7], *bf1a = d_in[8], *Wf1b = d_in[9], *bf1b = d_in[10];
    const void *Wf1c = d_in[11], *bf1c = d_in[12];
    const void *Wf2a = d_in[13], *bf2a = d_in[14], *Wf2b = d_in[15], *bf2b = d_in[16];
    const void *Wf2c = d_in[17], *bf2c = d_in[18];

    // Cross-kernel state: [0]=scale_bits, [1]=scale, [2]=dtype flag, [4..]=centers
    // (98.3 KB). Prefer d_ws; fall back to overlaying low d_out (safe: encdec
    // maps blockIdx->patch in reverse, overlay clobbered only by last blocks).
    float* ov = (ws_size >= (size_t)131072) ? (float*)d_ws : (float*)d_out;
    unsigned int* wbase   = (unsigned int*)ov;
    float*        scale_v = ov + 1;
    unsigned int* flagp   = wbase + 2;
    float*        centers = ov + 4;                // 24576 floats

    init_kernel<<<1, 1, 0, stream>>>(wbase);
    detect_kernel<<<256, 256, 0, stream>>>(data, flagp);
    fps_kernel<false><<<NB, 1024, 0, stream>>>(data, flagp, centers);
    fps_kernel<true ><<<NB, 1024, 0, stream>>>(data, flagp, centers);
    knn_kernel<false><<<NB * NC, 256, 0, stream>>>(data, perm, centers, flagp, wbase);
    knn_kernel<true ><<<NB * NC, 256, 0, stream>>>(data, perm, centers, flagp, wbase);
    finalize_kernel<<<1, 1, 0, stream>>>(wbase, scale_v);
    encdec_kernel<false><<<NB * NC, 256, 0, stream>>>(data, perm, centers, scale_v, flagp,
            grid, We1, be1, We2, be2, Wf1a, bf1a, Wf1b, bf1b, Wf1c, bf1c,
            Wf2a, bf2a, Wf2b, bf2b, Wf2c, bf2c, d_out);
    encdec_kernel<true ><<<NB * NC, 256, 0, stream>>>(data, perm, centers, scale_v, flagp,
            grid, We1, be1, We2, be2, Wf1a, bf1a, Wf1b, bf1b, Wf1c, bf1c,
            Wf2a, bf2a, Wf2b, bf2b, Wf2c, bf2c, d_out);
}

// Round 5
// 1514.090 us; speedup vs baseline: 2.0735x; 2.0735x over previous
//
#include <hip/hip_runtime.h>

#define NB 32
#define NN 8192
#define NC 256
#define NP 32
#define MYFLT_MAX 3.402823466e+38f

typedef __attribute__((ext_vector_type(8))) short short8;
typedef __attribute__((ext_vector_type(4))) float f32x4;

__device__ __forceinline__ float b2f(unsigned short u) {
    return __uint_as_float(((unsigned)u) << 16);
}
__device__ __forceinline__ unsigned short f2b(float f) {
    unsigned u = __float_as_uint(f);
    unsigned r = u + 0x7fffu + ((u >> 16) & 1u);
    return (unsigned short)(r >> 16);
}
template<bool F32>
__device__ __forceinline__ float LD(const void* __restrict__ p, size_t i) {
    if (F32) return ((const float* __restrict__)p)[i];
    else     return b2f(((const unsigned short* __restrict__)p)[i]);
}
// exact f32, no FMA contraction, reference association ((x*x + y*y) + z*z)
__device__ __forceinline__ float sq3(float x, float y, float z) {
    return __fadd_rn(__fadd_rn(__fmul_rn(x, x), __fmul_rn(y, y)), __fmul_rn(z, z));
}

// ---------------------------------------------------------------- init
__global__ void init_kernel(unsigned int* w) {
    w[0] = 0u;   // scale_bits
    w[2] = 0u;   // dtype flag (0 = bf16, >0 = f32)
}

// ---------------------------------------------------------------- dtype probe
__global__ __launch_bounds__(256) void detect_kernel(
        const void* __restrict__ data, unsigned int* __restrict__ flag) {
    const unsigned short* u = (const unsigned short*)data;
    int t = blockIdx.x * 256 + threadIdx.x;
    unsigned cnt = 0;
    for (size_t i = (size_t)t * 2; i < 786432; i += 131072)
        if ((u[i] & 0x7F80u) == 0x7F80u) cnt++;
    if (cnt) atomicAdd(flag, cnt);
}

// ---------------------------------------------------------------- weight prep (bf16 swizzle into ws)
// B-frag layout for mfma_f32_16x16x32_bf16: lane=(n&15)+16*((k&31)>>3), j=k&7
__device__ __forceinline__ size_t bfrag_idx(int k, int n, int nks) {
    int nt = n >> 4, ks = k >> 5;
    int lane = (n & 15) + 16 * ((k & 31) >> 3);
    return ((size_t)(nt * nks + ks) * 64 + lane) * 8 + (k & 7);
}
template<bool F32>
__global__ __launch_bounds__(256) void prep_kernel(
        const void* __restrict__ We2, const void* __restrict__ Wf1b,
        const void* __restrict__ Wf2b, const void* __restrict__ Wf1a,
        const void* __restrict__ Wf2a, const unsigned int* __restrict__ flagp,
        unsigned short* __restrict__ We2_sw, unsigned short* __restrict__ Wf1b_sw,
        unsigned short* __restrict__ Wf2b_sw, unsigned int* __restrict__ p1,
        unsigned int* __restrict__ p2) {
    if ((flagp[0] != 0u) != F32) return;
    int i = blockIdx.x * 256 + threadIdx.x;          // 163840 total
    if (i < 32768) {                                  // We2 [128,256]
        int k = i >> 8, n = i & 255;
        We2_sw[bfrag_idx(k, n, 4)] = f2b(LD<F32>(We2, i));
    } else if (i < 65536) {                           // Wf1b [256,128]
        int j = i - 32768, k = j >> 7, n = j & 127;
        Wf1b_sw[bfrag_idx(k, n, 8)] = f2b(LD<F32>(Wf1b, j));
    } else if (i < 98304) {                           // Wf2b [256,128]
        int j = i - 65536, k = j >> 7, n = j & 127;
        Wf2b_sw[bfrag_idx(k, n, 8)] = f2b(LD<F32>(Wf2b, j));
    } else if (i < 131072) {                          // Wf1a rows 0..255 paired
        int j = i - 98304, k2 = j >> 8, c = j & 255;
        unsigned lo = f2b(LD<F32>(Wf1a, (size_t)(2 * k2) * 256 + c));
        unsigned hi = f2b(LD<F32>(Wf1a, (size_t)(2 * k2 + 1) * 256 + c));
        p1[j] = lo | (hi << 16);
    } else {                                          // Wf2a rows 0..255 paired
        int j = i - 131072, k2 = j >> 8, c = j & 255;
        unsigned lo = f2b(LD<F32>(Wf2a, (size_t)(2 * k2) * 256 + c));
        unsigned hi = f2b(LD<F32>(Wf2a, (size_t)(2 * k2 + 1) * 256 + c));
        p2[j] = lo | (hi << 16);
    }
}

// ---------------------------------------------------------------- FPS
template<bool F32>
__global__ __launch_bounds__(1024) void fps_kernel(
        const void* __restrict__ data, const unsigned int* __restrict__ flagp,
        float* __restrict__ centers) {
    __shared__ float rv[16];
    __shared__ int   ri[16];
    __shared__ int   winIdx;
    __shared__ float winPt[4];
    if ((flagp[0] != 0u) != F32) return;
    const int b = blockIdx.x, tid = threadIdx.x;
    const size_t base = (size_t)b * 3 * NN;
    const float x0 = LD<F32>(data, base);
    const float y0 = LD<F32>(data, base + NN);
    const float z0 = LD<F32>(data, base + 2 * NN);
    float px[8], py[8], pz[8], mind[8];
#pragma unroll
    for (int j = 0; j < 8; j++) {
        int n = tid + 1024 * j;
        px[j] = LD<F32>(data, base + n);
        py[j] = LD<F32>(data, base + NN + n);
        pz[j] = LD<F32>(data, base + 2 * NN + n);
        mind[j] = sq3(__fsub_rn(px[j], x0), __fsub_rn(py[j], y0), __fsub_rn(pz[j], z0));
    }
    if (tid == 0) {
        centers[(b * NC + 0) * 3 + 0] = x0;
        centers[(b * NC + 0) * 3 + 1] = y0;
        centers[(b * NC + 0) * 3 + 2] = z0;
    }
    for (int i = 1; i < NC; i++) {
        float bv = mind[0]; int bn = tid;
#pragma unroll
        for (int j = 1; j < 8; j++)
            if (mind[j] > bv) { bv = mind[j]; bn = tid + 1024 * j; }
#pragma unroll
        for (int off = 32; off >= 1; off >>= 1) {
            float ov = __shfl_down(bv, off);
            int   on = __shfl_down(bn, off);
            if (ov > bv || (ov == bv && on < bn)) { bv = ov; bn = on; }
        }
        if ((tid & 63) == 0) { rv[tid >> 6] = bv; ri[tid >> 6] = bn; }
        __syncthreads();
        if (tid == 0) {
            float cv = rv[0]; int cn = ri[0];
#pragma unroll
            for (int w = 1; w < 16; w++)
                if (rv[w] > cv || (rv[w] == cv && ri[w] < cn)) { cv = rv[w]; cn = ri[w]; }
            if ((unsigned)cn >= NN) cn = 0;
            winIdx = cn;
        }
        __syncthreads();
        const int g = winIdx;
        if ((g & 1023) == tid) {
            int j = g >> 10;
            winPt[0] = px[j]; winPt[1] = py[j]; winPt[2] = pz[j];
        }
        __syncthreads();
        const float cx = winPt[0], cy = winPt[1], cz = winPt[2];
#pragma unroll
        for (int j = 0; j < 8; j++) {
            float d = sq3(__fsub_rn(px[j], cx), __fsub_rn(py[j], cy), __fsub_rn(pz[j], cz));
            mind[j] = fminf(mind[j], d);
        }
        if (tid == 0) {
            centers[(b * NC + i) * 3 + 0] = cx;
            centers[(b * NC + i) * 3 + 1] = cy;
            centers[(b * NC + i) * 3 + 2] = cz;
        }
    }
}

// ---------------------------------------------------------------- kNN: scale (+optional sel/cmean)
template<bool F32>
__global__ __launch_bounds__(256) void knn_kernel(
        const void* __restrict__ data, const int* __restrict__ perm,
        const float* __restrict__ centers, const unsigned int* __restrict__ flagp,
        unsigned int* __restrict__ scale_bits,
        int* __restrict__ selp, float* __restrict__ cmp) {
    __shared__ float dist[NN];
    __shared__ float rv4[4];
    __shared__ int   ri4[4];
    __shared__ int   winbuf;
    __shared__ int   sel[NP];
    if ((flagp[0] != 0u) != F32) return;
    const int m = blockIdx.x, b = m >> 8, c = m & 255, tid = threadIdx.x;
    const int ci = perm[c];
    const float cx = centers[((size_t)b * NC + ci) * 3 + 0];
    const float cy = centers[((size_t)b * NC + ci) * 3 + 1];
    const float cz = centers[((size_t)b * NC + ci) * 3 + 2];
    const float cn2 = sq3(cx, cy, cz);
    const size_t base = (size_t)b * 3 * NN;

    float bv = MYFLT_MAX; int bn = tid;
#pragma unroll 4
    for (int j = 0; j < 32; j++) {
        int n = tid + 256 * j;
        float x = LD<F32>(data, base + n);
        float y = LD<F32>(data, base + NN + n);
        float z = LD<F32>(data, base + 2 * NN + n);
        float pn2 = sq3(x, y, z);
        float dot = __fadd_rn(__fadd_rn(__fmul_rn(cx, x), __fmul_rn(cy, y)), __fmul_rn(cz, z));
        float d = __fsub_rn(__fadd_rn(cn2, pn2), __fmul_rn(2.0f, dot));
        dist[n] = d;
        if (d < bv) { bv = d; bn = n; }
    }
    for (int r = 0; r < NP; r++) {
        float v = bv; int n = bn;
#pragma unroll
        for (int off = 32; off >= 1; off >>= 1) {
            float ov = __shfl_down(v, off);
            int   on = __shfl_down(n, off);
            if (ov < v || (ov == v && on < n)) { v = ov; n = on; }
        }
        if ((tid & 63) == 0) { rv4[tid >> 6] = v; ri4[tid >> 6] = n; }
        __syncthreads();
        if (tid == 0) {
            float cv = rv4[0]; int cn = ri4[0];
#pragma unroll
            for (int w = 1; w < 4; w++)
                if (rv4[w] < cv || (rv4[w] == cv && ri4[w] < cn)) { cv = rv4[w]; cn = ri4[w]; }
            if ((unsigned)cn >= NN) cn = 0;
            winbuf = cn; sel[r] = cn;
        }
        __syncthreads();
        const int g = winbuf;
        if ((g & 255) == tid) {
            dist[g] = MYFLT_MAX;
            bv = MYFLT_MAX; bn = tid;
#pragma unroll 4
            for (int j = 0; j < 32; j++) {
                int nn2 = tid + 256 * j;
                float v2 = dist[nn2];
                if (v2 < bv) { bv = v2; bn = nn2; }
            }
        }
    }
    __syncthreads();
    if (tid < 32) {
        const int g = sel[tid];
        if (selp) selp[(size_t)m * 32 + tid] = g;
        float x = LD<F32>(data, base + g);
        float y = LD<F32>(data, base + NN + g);
        float z = LD<F32>(data, base + 2 * NN + g);
        float sx = x, sy = y, sz = z;
#pragma unroll
        for (int msk = 16; msk >= 1; msk >>= 1) {
            sx += __shfl_xor(sx, msk);
            sy += __shfl_xor(sy, msk);
            sz += __shfl_xor(sz, msk);
        }
        float mx = sx / 32.0f, my = sy / 32.0f, mz = sz / 32.0f;
        if (cmp && tid == 0) {
            cmp[(size_t)m * 3 + 0] = mx;
            cmp[(size_t)m * 3 + 1] = my;
            cmp[(size_t)m * 3 + 2] = mz;
        }
        float lx = x - mx, ly = y - my, lz = z - mz;
        float n2 = sq3(lx, ly, lz);
#pragma unroll
        for (int msk = 16; msk >= 1; msk >>= 1)
            n2 = fmaxf(n2, __shfl_xor(n2, msk));
        if (tid == 0) atomicMax(scale_bits, __float_as_uint(n2));
    }
}

// ---------------------------------------------------------------- scale
__global__ void finalize_kernel(const unsigned int* scale_bits, float* scale_v) {
    scale_v[0] = sqrtf(__uint_as_float(scale_bits[0]));
}

// ================================================================ MFMA encdec (big-ws path)
// A-frag write helper: element (m=p, k=c) of a [32 x K] A matrix, 16x16x32 tiles
__device__ __forceinline__ int afrag_idx(int p, int c) {
    int ks = c >> 5, mt = p >> 4;
    int lane = (p & 15) + 16 * ((c & 31) >> 3);
    return ((ks * 2 + mt) * 64 + lane) * 8 + (c & 7);
}

template<bool F32>
__global__ __launch_bounds__(256) void encdec_mfma(
        const void* __restrict__ data, const int* __restrict__ selp,
        const float* __restrict__ cmp, const float* __restrict__ scale_p,
        const unsigned int* __restrict__ flagp, const void* __restrict__ gridw,
        const void* __restrict__ We1, const void* __restrict__ be1,
        const unsigned short* __restrict__ We2_sw, const void* __restrict__ be2,
        const void* __restrict__ Wf1a, const unsigned int* __restrict__ p1,
        const void* __restrict__ bf1a,
        const unsigned short* __restrict__ Wf1b_sw, const void* __restrict__ bf1b,
        const void* __restrict__ Wf1c, const void* __restrict__ bf1c,
        const void* __restrict__ Wf2a, const unsigned int* __restrict__ p2,
        const void* __restrict__ bf2a,
        const unsigned short* __restrict__ Wf2b_sw, const void* __restrict__ bf2b,
        const void* __restrict__ Wf2c, const void* __restrict__ bf2c,
        void* __restrict__ out) {
    __shared__ unsigned short afrag[8192];   // 16 KB A-fragments (bf16)
    __shared__ float g2s[32 * 132];          // 16.9 KB [p][j] (+pad)
    __shared__ float code[256];
    __shared__ float xb[96];
    __shared__ float fb[96];
    __shared__ float gridb[64];
    if ((flagp[0] != 0u) != F32) return;
    const int m = blockIdx.x, b = m >> 8, tid = threadIdx.x;
    const int wv = tid >> 6, lane = tid & 63;
    const float scale = scale_p[0];
    const size_t base = (size_t)b * 3 * NN;
    if (tid < 64) gridb[tid] = LD<F32>(gridw, tid);
    if (tid < 32) {
        const int g = selp[(size_t)m * 32 + tid];
        xb[tid * 3 + 0] = (LD<F32>(data, base + g)          - cmp[(size_t)m * 3 + 0]) / scale;
        xb[tid * 3 + 1] = (LD<F32>(data, base + NN + g)     - cmp[(size_t)m * 3 + 1]) / scale;
        xb[tid * 3 + 2] = (LD<F32>(data, base + 2 * NN + g) - cmp[(size_t)m * 3 + 2]) / scale;
    }
    __syncthreads();
    // ---- E2: h1 = relu(x@We1+be1) -> afrag (A of [32p x 128k]) ----
    for (int o = tid; o < 4096; o += 256) {
        int p = o >> 7, ch = o & 127;
        float v = xb[p * 3 + 0] * LD<F32>(We1, ch) + xb[p * 3 + 1] * LD<F32>(We1, 128 + ch)
                + xb[p * 3 + 2] * LD<F32>(We1, 256 + ch) + LD<F32>(be1, ch);
        afrag[afrag_idx(p, ch)] = f2b(fmaxf(v, 0.0f));
    }
    __syncthreads();
    // ---- E3: code = relu(max_p(h1@We2) + be2) via MFMA; wave wv -> n in [64wv,64wv+64) ----
    {
        f32x4 acc[2][4];
#pragma unroll
        for (int a = 0; a < 2; a++)
#pragma unroll
            for (int t = 0; t < 4; t++) acc[a][t] = (f32x4){0.f, 0.f, 0.f, 0.f};
#pragma unroll
        for (int ks = 0; ks < 4; ks++) {
            short8 a0 = *(const short8*)&afrag[((ks * 2 + 0) * 64 + lane) * 8];
            short8 a1 = *(const short8*)&afrag[((ks * 2 + 1) * 64 + lane) * 8];
#pragma unroll
            for (int nt = 0; nt < 4; nt++) {
                short8 bf = *(const short8*)&We2_sw[((size_t)((4 * wv + nt) * 4 + ks) * 64 + lane) * 8];
                acc[0][nt] = __builtin_amdgcn_mfma_f32_16x16x32_bf16(a0, bf, acc[0][nt], 0, 0, 0);
                acc[1][nt] = __builtin_amdgcn_mfma_f32_16x16x32_bf16(a1, bf, acc[1][nt], 0, 0, 0);
            }
        }
#pragma unroll
        for (int nt = 0; nt < 4; nt++) {
            float mx = acc[0][nt][0];
#pragma unroll
            for (int r = 1; r < 4; r++) mx = fmaxf(mx, acc[0][nt][r]);
#pragma unroll
            for (int r = 0; r < 4; r++) mx = fmaxf(mx, acc[1][nt][r]);
            mx = fmaxf(mx, __shfl_xor(mx, 16));
            mx = fmaxf(mx, __shfl_xor(mx, 32));
            int n = 64 * wv + nt * 16 + (lane & 15);
            if (lane < 16) code[n] = fmaxf(mx + LD<F32>(be2, n), 0.0f);
        }
    }
    __syncthreads();
    // ---- D1: g1 = relu(code@Wf1a + bf1a + grid terms) -> afrag (A of [32p x 256k]) ----
    {
        float a0 = 0.f, a1 = 0.f;
#pragma unroll 8
        for (int k2 = 0; k2 < 128; k2++) {
            unsigned u = p1[k2 * 256 + tid];
            a0 = fmaf(code[2 * k2],     b2f((unsigned short)(u & 0xffffu)), a0);
            a1 = fmaf(code[2 * k2 + 1], b2f((unsigned short)(u >> 16)), a1);
        }
        float base1 = a0 + a1 + LD<F32>(bf1a, tid);
        float wu = LD<F32>(Wf1a, 65536 + tid);
        float wvv = LD<F32>(Wf1a, 65792 + tid);
#pragma unroll 8
        for (int p = 0; p < 32; p++) {
            float v = base1 + gridb[2 * p] * wu + gridb[2 * p + 1] * wvv;
            afrag[afrag_idx(p, tid)] = f2b(fmaxf(v, 0.0f));
        }
    }
    __syncthreads();
    // ---- D2: g2 = relu(g1@Wf1b + bf1b) via MFMA -> g2s; wave wv -> n in [32wv,32wv+32) ----
    {
        f32x4 acc[2][2];
#pragma unroll
        for (int a = 0; a < 2; a++)
#pragma unroll
            for (int t = 0; t < 2; t++) acc[a][t] = (f32x4){0.f, 0.f, 0.f, 0.f};
#pragma unroll
        for (int ks = 0; ks < 8; ks++) {
            short8 a0 = *(const short8*)&afrag[((ks * 2 + 0) * 64 + lane) * 8];
            short8 a1 = *(const short8*)&afrag[((ks * 2 + 1) * 64 + lane) * 8];
#pragma unroll
            for (int nt = 0; nt < 2; nt++) {
                short8 bf = *(const short8*)&Wf1b_sw[((size_t)((2 * wv + nt) * 8 + ks) * 64 + lane) * 8];
                acc[0][nt] = __builtin_amdgcn_mfma_f32_16x16x32_bf16(a0, bf, acc[0][nt], 0, 0, 0);
                acc[1][nt] = __builtin_amdgcn_mfma_f32_16x16x32_bf16(a1, bf, acc[1][nt], 0, 0, 0);
            }
        }
#pragma unroll
        for (int nt = 0; nt < 2; nt++) {
            int n = 32 * wv + nt * 16 + (lane & 15);
            float bb = LD<F32>(bf1b, n);
#pragma unroll
            for (int mt = 0; mt < 2; mt++)
#pragma unroll
                for (int r = 0; r < 4; r++) {
                    int mm = mt * 16 + (lane >> 4) * 4 + r;
                    g2s[mm * 132 + n] = fmaxf(acc[mt][nt][r] + bb, 0.0f);
                }
        }
    }
    __syncthreads();
    // ---- D3: fb = g2@Wf1c + bf1c ----
    if (tid < 96) {
        int p = tid / 3, e = tid % 3;
        float acc = 0.0f;
#pragma unroll 8
        for (int k = 0; k < 128; k++)
            acc = fmaf(g2s[p * 132 + k], LD<F32>(Wf1c, k * 3 + e), acc);
        fb[tid] = acc + LD<F32>(bf1c, e);
    }
    __syncthreads();
    // ---- D4: g1' = relu(code@Wf2a + bf2a + f terms) -> afrag ----
    {
        float a0 = 0.f, a1 = 0.f;
#pragma unroll 8
        for (int k2 = 0; k2 < 128; k2++) {
            unsigned u = p2[k2 * 256 + tid];
            a0 = fmaf(code[2 * k2],     b2f((unsigned short)(u & 0xffffu)), a0);
            a1 = fmaf(code[2 * k2 + 1], b2f((unsigned short)(u >> 16)), a1);
        }
        float base2 = a0 + a1 + LD<F32>(bf2a, tid);
        float w0 = LD<F32>(Wf2a, 65536 + tid);
        float w1 = LD<F32>(Wf2a, 65792 + tid);
        float w2 = LD<F32>(Wf2a, 66048 + tid);
#pragma unroll 8
        for (int p = 0; p < 32; p++) {
            float v = base2 + fb[p * 3] * w0 + fb[p * 3 + 1] * w1 + fb[p * 3 + 2] * w2;
            afrag[afrag_idx(p, tid)] = f2b(fmaxf(v, 0.0f));
        }
    }
    __syncthreads();
    // ---- D5: g2' = relu(g1'@Wf2b + bf2b) via MFMA -> g2s ----
    {
        f32x4 acc[2][2];
#pragma unroll
        for (int a = 0; a < 2; a++)
#pragma unroll
            for (int t = 0; t < 2; t++) acc[a][t] = (f32x4){0.f, 0.f, 0.f, 0.f};
#pragma unroll
        for (int ks = 0; ks < 8; ks++) {
            short8 a0 = *(const short8*)&afrag[((ks * 2 + 0) * 64 + lane) * 8];
            short8 a1 = *(const short8*)&afrag[((ks * 2 + 1) * 64 + lane) * 8];
#pragma unroll
            for (int nt = 0; nt < 2; nt++) {
                short8 bf = *(const short8*)&Wf2b_sw[((size_t)((2 * wv + nt) * 8 + ks) * 64 + lane) * 8];
                acc[0][nt] = __builtin_amdgcn_mfma_f32_16x16x32_bf16(a0, bf, acc[0][nt], 0, 0, 0);
                acc[1][nt] = __builtin_amdgcn_mfma_f32_16x16x32_bf16(a1, bf, acc[1][nt], 0, 0, 0);
            }
        }
#pragma unroll
        for (int nt = 0; nt < 2; nt++) {
            int n = 32 * wv + nt * 16 + (lane & 15);
            float bb = LD<F32>(bf2b, n);
#pragma unroll
            for (int mt = 0; mt < 2; mt++)
#pragma unroll
                for (int r = 0; r < 4; r++) {
                    int mm = mt * 16 + (lane >> 4) * 4 + r;
                    g2s[mm * 132 + n] = fmaxf(acc[mt][nt][r] + bb, 0.0f);
                }
        }
    }
    __syncthreads();
    // ---- D6: out = (g2'@Wf2c + bf2c)*scale + cmean ----
    if (tid < 96) {
        int p = tid / 3, e = tid % 3;
        float acc = 0.0f;
#pragma unroll 8
        for (int k = 0; k < 128; k++)
            acc = fmaf(g2s[p * 132 + k], LD<F32>(Wf2c, k * 3 + e), acc);
        float v = (acc + LD<F32>(bf2c, e)) * scale + cmp[(size_t)m * 3 + e];
        size_t oi = (size_t)m * 96 + tid;
        if (F32) ((float*)out)[oi] = v;
        else     ((unsigned short*)out)[oi] = f2b(v);
    }
}

// ================================================================ fallback fused encdec (R4)
template<bool F32>
__global__ __launch_bounds__(256) void encdec_fused(
        const void* __restrict__ data,
        const int* __restrict__ perm, const float* __restrict__ centers,
        const float* __restrict__ scale_p, const unsigned int* __restrict__ flagp,
        const void* __restrict__ gridw,
        const void* __restrict__ We1, const void* __restrict__ be1,
        const void* __restrict__ We2, const void* __restrict__ be2,
        const void* __restrict__ Wf1a, const void* __restrict__ bf1a,
        const void* __restrict__ Wf1b, const void* __restrict__ bf1b,
        const void* __restrict__ Wf1c, const void* __restrict__ bf1c,
        const void* __restrict__ Wf2a, const void* __restrict__ bf2a,
        const void* __restrict__ Wf2b, const void* __restrict__ bf2b,
        const void* __restrict__ Wf2c, const void* __restrict__ bf2c,
        void* __restrict__ out) {
    __shared__ float bigA[256 * 36];
    __shared__ float bigB[128 * 36];
    __shared__ float code[256];
    __shared__ float xb[96];
    __shared__ float fb[96];
    __shared__ float gridb[64];
    __shared__ float meansh[4];
    __shared__ float rv4[4];
    __shared__ int   ri4[4];
    __shared__ int   winbuf;
    __shared__ int   sel[NP];
    if ((flagp[0] != 0u) != F32) return;
    const int m = (NB * NC - 1) - blockIdx.x;
    const int b = m >> 8, c = m & 255, tid = threadIdx.x;
    const float scale = scale_p[0];
    const int ci = perm[c];
    const float cx = centers[((size_t)b * NC + ci) * 3 + 0];
    const float cy = centers[((size_t)b * NC + ci) * 3 + 1];
    const float cz = centers[((size_t)b * NC + ci) * 3 + 2];
    const float cn2 = sq3(cx, cy, cz);
    const size_t base = (size_t)b * 3 * NN;
    if (tid < 64) gridb[tid] = LD<F32>(gridw, tid);
    float* dist = bigA;
    float bv = MYFLT_MAX; int bn = tid;
#pragma unroll 4
    for (int j = 0; j < 32; j++) {
        int n = tid + 256 * j;
        float x = LD<F32>(data, base + n);
        float y = LD<F32>(data, base + NN + n);
        float z = LD<F32>(data, base + 2 * NN + n);
        float pn2 = sq3(x, y, z);
        float dot = __fadd_rn(__fadd_rn(__fmul_rn(cx, x), __fmul_rn(cy, y)), __fmul_rn(cz, z));
        float d = __fsub_rn(__fadd_rn(cn2, pn2), __fmul_rn(2.0f, dot));
        dist[n] = d;
        if (d < bv) { bv = d; bn = n; }
    }
    for (int r = 0; r < NP; r++) {
        float v = bv; int n = bn;
#pragma unroll
        for (int off = 32; off >= 1; off >>= 1) {
            float ov = __shfl_down(v, off);
            int   on = __shfl_down(n, off);
            if (ov < v || (ov == v && on < n)) { v = ov; n = on; }
        }
        if ((tid & 63) == 0) { rv4[tid >> 6] = v; ri4[tid >> 6] = n; }
        __syncthreads();
        if (tid == 0) {
            float cv = rv4[0]; int cn = ri4[0];
#pragma unroll
            for (int w = 1; w < 4; w++)
                if (rv4[w] < cv || (rv4[w] == cv && ri4[w] < cn)) { cv = rv4[w]; cn = ri4[w]; }
            if ((unsigned)cn >= NN) cn = 0;
            winbuf = cn; sel[r] = cn;
        }
        __syncthreads();
        const int g = winbuf;
        if ((g & 255) == tid) {
            dist[g] = MYFLT_MAX;
            bv = MYFLT_MAX; bn = tid;
#pragma unroll 4
            for (int j = 0; j < 32; j++) {
                int nn2 = tid + 256 * j;
                float v2 = dist[nn2];
                if (v2 < bv) { bv = v2; bn = nn2; }
            }
        }
    }
    __syncthreads();
    if (tid < 32) {
        const int g = sel[tid];
        float x = LD<F32>(data, base + g);
        float y = LD<F32>(data, base + NN + g);
        float z = LD<F32>(data, base + 2 * NN + g);
        float sx = x, sy = y, sz = z;
#pragma unroll
        for (int msk = 16; msk >= 1; msk >>= 1) {
            sx += __shfl_xor(sx, msk);
            sy += __shfl_xor(sy, msk);
            sz += __shfl_xor(sz, msk);
        }
        float mx = sx / 32.0f, my = sy / 32.0f, mz = sz / 32.0f;
        xb[tid * 3 + 0] = (x - mx) / scale;
        xb[tid * 3 + 1] = (y - my) / scale;
        xb[tid * 3 + 2] = (z - mz) / scale;
        if (tid == 0) { meansh[0] = mx; meansh[1] = my; meansh[2] = mz; }
    }
    __syncthreads();
    for (int o = tid; o < 4096; o += 256) {
        int p = o >> 7, i = o & 127;
        float v = xb[p * 3 + 0] * LD<F32>(We1, i) + xb[p * 3 + 1] * LD<F32>(We1, 128 + i)
                + xb[p * 3 + 2] * LD<F32>(We1, 256 + i) + LD<F32>(be1, i);
        bigB[i * 36 + p] = fmaxf(v, 0.0f);
    }
    __syncthreads();
    {
        float acc[32];
#pragma unroll
        for (int p = 0; p < 32; p++) acc[p] = 0.0f;
        for (int k = 0; k < 128; k++) {
            float w = LD<F32>(We2, k * 256 + tid);
            const float4* hp = (const float4*)&bigB[k * 36];
#pragma unroll
            for (int q = 0; q < 8; q++) {
                float4 h4 = hp[q];
                acc[q * 4 + 0] = fmaf(h4.x, w, acc[q * 4 + 0]);
                acc[q * 4 + 1] = fmaf(h4.y, w, acc[q * 4 + 1]);
                acc[q * 4 + 2] = fmaf(h4.z, w, acc[q * 4 + 2]);
                acc[q * 4 + 3] = fmaf(h4.w, w, acc[q * 4 + 3]);
            }
        }
        float mx = acc[0];
#pragma unroll
        for (int p = 1; p < 32; p++) mx = fmaxf(mx, acc[p]);
        code[tid] = fmaxf(mx + LD<F32>(be2, tid), 0.0f);
    }
    __syncthreads();
    {
        float a0 = 0.f, a1 = 0.f, a2 = 0.f, a3 = 0.f;
        for (int k = 0; k < 256; k += 4) {
            a0 = fmaf(code[k + 0], LD<F32>(Wf1a, (k + 0) * 256 + tid), a0);
            a1 = fmaf(code[k + 1], LD<F32>(Wf1a, (k + 1) * 256 + tid), a1);
            a2 = fmaf(code[k + 2], LD<F32>(Wf1a, (k + 2) * 256 + tid), a2);
            a3 = fmaf(code[k + 3], LD<F32>(Wf1a, (k + 3) * 256 + tid), a3);
        }
        float base1 = ((a0 + a1) + (a2 + a3)) + LD<F32>(bf1a, tid);
        float wu = LD<F32>(Wf1a, 65536 + tid);
        float wvv = LD<F32>(Wf1a, 65792 + tid);
#pragma unroll 8
        for (int p = 0; p < 32; p++) {
            float v = base1 + gridb[2 * p] * wu + gridb[2 * p + 1] * wvv;
            bigA[tid * 36 + p] = fmaxf(v, 0.0f);
        }
    }
    __syncthreads();
    {
        int j = tid & 127, ph = tid >> 7;
        float acc[16];
#pragma unroll
        for (int q = 0; q < 16; q++) acc[q] = 0.0f;
        for (int k = 0; k < 256; k++) {
            float w = LD<F32>(Wf1b, k * 128 + j);
            const float4* gp = (const float4*)&bigA[k * 36 + ph * 16];
            float4 h0 = gp[0], h1 = gp[1], h2 = gp[2], h3 = gp[3];
            acc[0] = fmaf(h0.x, w, acc[0]);   acc[1] = fmaf(h0.y, w, acc[1]);
            acc[2] = fmaf(h0.z, w, acc[2]);   acc[3] = fmaf(h0.w, w, acc[3]);
            acc[4] = fmaf(h1.x, w, acc[4]);   acc[5] = fmaf(h1.y, w, acc[5]);
            acc[6] = fmaf(h1.z, w, acc[6]);   acc[7] = fmaf(h1.w, w, acc[7]);
            acc[8] = fmaf(h2.x, w, acc[8]);   acc[9] = fmaf(h2.y, w, acc[9]);
            acc[10] = fmaf(h2.z, w, acc[10]); acc[11] = fmaf(h2.w, w, acc[11]);
            acc[12] = fmaf(h3.x, w, acc[12]); acc[13] = fmaf(h3.y, w, acc[13]);
            acc[14] = fmaf(h3.z, w, acc[14]); acc[15] = fmaf(h3.w, w, acc[15]);
        }
        float bb = LD<F32>(bf1b, j);
#pragma unroll
        for (int q = 0; q < 16; q++)
            bigB[j * 36 + ph * 16 + q] = fmaxf(acc[q] + bb, 0.0f);
    }
    __syncthreads();
    if (tid < 96) {
        int p = tid / 3, e = tid % 3;
        float acc = 0.0f;
        for (int k = 0; k < 128; k++)
            acc = fmaf(bigB[k * 36 + p], LD<F32>(Wf1c, k * 3 + e), acc);
        fb[tid] = acc + LD<F32>(bf1c, e);
    }
    __syncthreads();
    {
        float a0 = 0.f, a1 = 0.f, a2 = 0.f, a3 = 0.f;
        for (int k = 0; k < 256; k += 4) {
            a0 = fmaf(code[k + 0], LD<F32>(Wf2a, (k + 0) * 256 + tid), a0);
            a1 = fmaf(code[k + 1], LD<F32>(Wf2a, (k + 1) * 256 + tid), a1);
            a2 = fmaf(code[k + 2], LD<F32>(Wf2a, (k + 2) * 256 + tid), a2);
            a3 = fmaf(code[k + 3], LD<F32>(Wf2a, (k + 3) * 256 + tid), a3);
        }
        float base2 = ((a0 + a1) + (a2 + a3)) + LD<F32>(bf2a, tid);
        float w0 = LD<F32>(Wf2a, 65536 + tid);
        float w1 = LD<F32>(Wf2a, 65792 + tid);
        float w2 = LD<F32>(Wf2a, 66048 + tid);
#pragma unroll 8
        for (int p = 0; p < 32; p++) {
            float v = base2 + fb[p * 3] * w0 + fb[p * 3 + 1] * w1 + fb[p * 3 + 2] * w2;
            bigA[tid * 36 + p] = fmaxf(v, 0.0f);
        }
    }
    __syncthreads();
    {
        int j = tid & 127, ph = tid >> 7;
        float acc[16];
#pragma unroll
        for (int q = 0; q < 16; q++) acc[q] = 0.0f;
        for (int k = 0; k < 256; k++) {
            float w = LD<F32>(Wf2b, k * 128 + j);
            const float4* gp = (const float4*)&bigA[k * 36 + ph * 16];
            float4 h0 = gp[0], h1 = gp[1], h2 = gp[2], h3 = gp[3];
            acc[0] = fmaf(h0.x, w, acc[0]);   acc[1] = fmaf(h0.y, w, acc[1]);
            acc[2] = fmaf(h0.z, w, acc[2]);   acc[3] = fmaf(h0.w, w, acc[3]);
            acc[4] = fmaf(h1.x, w, acc[4]);   acc[5] = fmaf(h1.y, w, acc[5]);
            acc[6] = fmaf(h1.z, w, acc[6]);   acc[7] = fmaf(h1.w, w, acc[7]);
            acc[8] = fmaf(h2.x, w, acc[8]);   acc[9] = fmaf(h2.y, w, acc[9]);
            acc[10] = fmaf(h2.z, w, acc[10]); acc[11] = fmaf(h2.w, w, acc[11]);
            acc[12] = fmaf(h3.x, w, acc[12]); acc[13] = fmaf(h3.y, w, acc[13]);
            acc[14] = fmaf(h3.z, w, acc[14]); acc[15] = fmaf(h3.w, w, acc[15]);
        }
        float bb = LD<F32>(bf2b, j);
#pragma unroll
        for (int q = 0; q < 16; q++)
            bigB[j * 36 + ph * 16 + q] = fmaxf(acc[q] + bb, 0.0f);
    }
    __syncthreads();
    if (tid < 96) {
        int p = tid / 3, e = tid % 3;
        float acc = 0.0f;
        for (int k = 0; k < 128; k++)
            acc = fmaf(bigB[k * 36 + p], LD<F32>(Wf2c, k * 3 + e), acc);
        float v = (acc + LD<F32>(bf2c, e)) * scale + meansh[e];
        size_t oi = (size_t)m * 96 + tid;
        if (F32) ((float*)out)[oi] = v;
        else     ((unsigned short*)out)[oi] = f2b(v);
    }
}

extern "C" void kernel_launch(void* const* d_in, const int* in_sizes, int n_in,
                              void* d_out, int out_size, void* d_ws, size_t ws_size,
                              hipStream_t stream) {
    const void* data = d_in[0];
    const int* perm  = (const int*)d_in[1];
    const void* grid = d_in[2];
    const void *We1 = d_in[3], *be1 = d_in[4], *We2 = d_in[5], *be2 = d_in[6];
    const void *Wf1a = d_in[7], *bf1a = d_in[8], *Wf1b = d_in[9], *bf1b = d_in[10];
    const void *Wf1c = d_in[11], *bf1c = d_in[12];
    const void *Wf2a = d_in[13], *bf2a = d_in[14], *Wf2b = d_in[15], *bf2b = d_in[16];
    const void *Wf2c = d_in[17], *bf2c = d_in[18];

    if (ws_size >= (size_t)4 * 1024 * 1024) {
        // ---------- big-ws MFMA path ----------
        float* ws = (float*)d_ws;
        unsigned int* wbase   = (unsigned int*)ws;     // [0]=scale_bits,[2]=flag
        float*        scale_v = ws + 1;
        unsigned int* flagp   = wbase + 2;
        float*        centers = ws + 4;                // 24576
        float*        cmeanp  = ws + 24580;            // 24576
        int*          selp    = (int*)(ws + 49156);    // 262144
        unsigned short* We2_sw  = (unsigned short*)(ws + 311304);  // 32768 bf16
        unsigned short* Wf1b_sw = (unsigned short*)(ws + 327688);
        unsigned short* Wf2b_sw = (unsigned short*)(ws + 344072);
        unsigned int*   p1      = (unsigned int*)(ws + 360456);    // 32768 u32
        unsigned int*   p2      = (unsigned int*)(ws + 393224);

        init_kernel<<<1, 1, 0, stream>>>(wbase);
        detect_kernel<<<256, 256, 0, stream>>>(data, flagp);
        prep_kernel<false><<<640, 256, 0, stream>>>(We2, Wf1b, Wf2b, Wf1a, Wf2a, flagp,
                                                    We2_sw, Wf1b_sw, Wf2b_sw, p1, p2);
        prep_kernel<true ><<<640, 256, 0, stream>>>(We2, Wf1b, Wf2b, Wf1a, Wf2a, flagp,
                                                    We2_sw, Wf1b_sw, Wf2b_sw, p1, p2);
        fps_kernel<false><<<NB, 1024, 0, stream>>>(data, flagp, centers);
        fps_kernel<true ><<<NB, 1024, 0, stream>>>(data, flagp, centers);
        knn_kernel<false><<<NB * NC, 256, 0, stream>>>(data, perm, centers, flagp, wbase, selp, cmeanp);
        knn_kernel<true ><<<NB * NC, 256, 0, stream>>>(data, perm, centers, flagp, wbase, selp, cmeanp);
        finalize_kernel<<<1, 1, 0, stream>>>(wbase, scale_v);
        encdec_mfma<false><<<NB * NC, 256, 0, stream>>>(data, selp, cmeanp, scale_v, flagp, grid,
                We1, be1, We2_sw, be2, Wf1a, p1, bf1a, Wf1b_sw, bf1b, Wf1c, bf1c,
                Wf2a, p2, bf2a, Wf2b_sw, bf2b, Wf2c, bf2c, d_out);
        encdec_mfma<true ><<<NB * NC, 256, 0, stream>>>(data, selp, cmeanp, scale_v, flagp, grid,
                We1, be1, We2_sw, be2, Wf1a, p1, bf1a, Wf1b_sw, bf1b, Wf1c, bf1c,
                Wf2a, p2, bf2a, Wf2b_sw, bf2b, Wf2c, bf2c, d_out);
    } else {
        // ---------- fallback: R4 path verbatim ----------
        float* ov = (ws_size >= (size_t)131072) ? (float*)d_ws : (float*)d_out;
        unsigned int* wbase   = (unsigned int*)ov;
        float*        scale_v = ov + 1;
        unsigned int* flagp   = wbase + 2;
        float*        centers = ov + 4;

        init_kernel<<<1, 1, 0, stream>>>(wbase);
        detect_kernel<<<256, 256, 0, stream>>>(data, flagp);
        fps_kernel<false><<<NB, 1024, 0, stream>>>(data, flagp, centers);
        fps_kernel<true ><<<NB, 1024, 0, stream>>>(data, flagp, centers);
        knn_kernel<false><<<NB * NC, 256, 0, stream>>>(data, perm, centers, flagp, wbase, nullptr, nullptr);
        knn_kernel<true ><<<NB * NC, 256, 0, stream>>>(data, perm, centers, flagp, wbase, nullptr, nullptr);
        finalize_kernel<<<1, 1, 0, stream>>>(wbase, scale_v);
        encdec_fused<false><<<NB * NC, 256, 0, stream>>>(data, perm, centers, scale_v, flagp,
                grid, We1, be1, We2, be2, Wf1a, bf1a, Wf1b, bf1b, Wf1c, bf1c,
                Wf2a, bf2a, Wf2b, bf2b, Wf2c, bf2c, d_out);
        encdec_fused<true ><<<NB * NC, 256, 0, stream>>>(data, perm, centers, scale_v, flagp,
                grid, We1, be1, We2, be2, Wf1a, bf1a, Wf1b, bf1b, Wf1c, bf1c,
                Wf2a, bf2a, Wf2b, bf2b, Wf2c, bf2c, d_out);
    }
}

// Round 6
// 1426.096 us; speedup vs baseline: 2.2014x; 1.0617x over previous
//
#include <hip/hip_runtime.h>

#define NB 32
#define NN 8192
#define NC 256
#define NP 32
#define MYFLT_MAX 3.402823466e+38f

typedef __attribute__((ext_vector_type(8))) short short8;
typedef __attribute__((ext_vector_type(4))) float f32x4;

__device__ __forceinline__ float b2f(unsigned short u) {
    return __uint_as_float(((unsigned)u) << 16);
}
__device__ __forceinline__ unsigned short f2b(float f) {
    unsigned u = __float_as_uint(f);
    unsigned r = u + 0x7fffu + ((u >> 16) & 1u);
    return (unsigned short)(r >> 16);
}
template<bool F32>
__device__ __forceinline__ float LD(const void* __restrict__ p, size_t i) {
    if (F32) return ((const float* __restrict__)p)[i];
    else     return b2f(((const unsigned short* __restrict__)p)[i]);
}
// exact f32, no FMA contraction, reference association ((x*x + y*y) + z*z)
__device__ __forceinline__ float sq3(float x, float y, float z) {
    return __fadd_rn(__fadd_rn(__fmul_rn(x, x), __fmul_rn(y, y)), __fmul_rn(z, z));
}

// ---------------------------------------------------------------- init
__global__ void init_kernel(unsigned int* w) {
    w[0] = 0u;   // scale_bits
    w[2] = 0u;   // dtype flag (0 = bf16, >0 = f32)
}

// ---------------------------------------------------------------- dtype probe
__global__ __launch_bounds__(256) void detect_kernel(
        const void* __restrict__ data, unsigned int* __restrict__ flag) {
    const unsigned short* u = (const unsigned short*)data;
    int t = blockIdx.x * 256 + threadIdx.x;
    unsigned cnt = 0;
    for (size_t i = (size_t)t * 2; i < 786432; i += 131072)
        if ((u[i] & 0x7F80u) == 0x7F80u) cnt++;
    if (cnt) atomicAdd(flag, cnt);
}

// ---------------------------------------------------------------- weight prep (bf16 swizzle into ws)
// B-frag layout for mfma_f32_16x16x32_bf16: lane=(n&15)+16*((k&31)>>3), j=k&7
__device__ __forceinline__ size_t bfrag_idx(int k, int n, int nks) {
    int nt = n >> 4, ks = k >> 5;
    int lane = (n & 15) + 16 * ((k & 31) >> 3);
    return ((size_t)(nt * nks + ks) * 64 + lane) * 8 + (k & 7);
}
template<bool F32>
__global__ __launch_bounds__(256) void prep_kernel(
        const void* __restrict__ We2, const void* __restrict__ Wf1b,
        const void* __restrict__ Wf2b, const void* __restrict__ Wf1a,
        const void* __restrict__ Wf2a, const unsigned int* __restrict__ flagp,
        unsigned short* __restrict__ We2_sw, unsigned short* __restrict__ Wf1b_sw,
        unsigned short* __restrict__ Wf2b_sw, unsigned int* __restrict__ p1,
        unsigned int* __restrict__ p2) {
    if ((flagp[0] != 0u) != F32) return;
    int i = blockIdx.x * 256 + threadIdx.x;          // 163840 total
    if (i < 32768) {                                  // We2 [128,256]
        int k = i >> 8, n = i & 255;
        We2_sw[bfrag_idx(k, n, 4)] = f2b(LD<F32>(We2, i));
    } else if (i < 65536) {                           // Wf1b [256,128]
        int j = i - 32768, k = j >> 7, n = j & 127;
        Wf1b_sw[bfrag_idx(k, n, 8)] = f2b(LD<F32>(Wf1b, j));
    } else if (i < 98304) {                           // Wf2b [256,128]
        int j = i - 65536, k = j >> 7, n = j & 127;
        Wf2b_sw[bfrag_idx(k, n, 8)] = f2b(LD<F32>(Wf2b, j));
    } else if (i < 131072) {                          // Wf1a rows 0..255 paired
        int j = i - 98304, k2 = j >> 8, c = j & 255;
        unsigned lo = f2b(LD<F32>(Wf1a, (size_t)(2 * k2) * 256 + c));
        unsigned hi = f2b(LD<F32>(Wf1a, (size_t)(2 * k2 + 1) * 256 + c));
        p1[j] = lo | (hi << 16);
    } else {                                          // Wf2a rows 0..255 paired
        int j = i - 131072, k2 = j >> 8, c = j & 255;
        unsigned lo = f2b(LD<F32>(Wf2a, (size_t)(2 * k2) * 256 + c));
        unsigned hi = f2b(LD<F32>(Wf2a, (size_t)(2 * k2 + 1) * 256 + c));
        p2[j] = lo | (hi << 16);
    }
}

// ---------------------------------------------------------------- FPS
// one block/batch; 1024 threads x 8 points in registers. Winner (dist,idx,x,y,z)
// tuple carried THROUGH the shuffle reductions: no owner-broadcast, no serial
// scan, 2 barriers/iteration.
template<bool F32>
__global__ __launch_bounds__(1024) void fps_kernel(
        const void* __restrict__ data, const unsigned int* __restrict__ flagp,
        float* __restrict__ centers) {
    __shared__ float rv[16], rx[16], ry[16], rz[16];
    __shared__ int   ri[16];
    __shared__ float winPt[4];
    if ((flagp[0] != 0u) != F32) return;
    const int b = blockIdx.x, tid = threadIdx.x;
    const size_t base = (size_t)b * 3 * NN;
    const float x0 = LD<F32>(data, base);
    const float y0 = LD<F32>(data, base + NN);
    const float z0 = LD<F32>(data, base + 2 * NN);
    float px[8], py[8], pz[8], mind[8];
#pragma unroll
    for (int j = 0; j < 8; j++) {
        int n = tid + 1024 * j;
        px[j] = LD<F32>(data, base + n);
        py[j] = LD<F32>(data, base + NN + n);
        pz[j] = LD<F32>(data, base + 2 * NN + n);
        mind[j] = sq3(__fsub_rn(px[j], x0), __fsub_rn(py[j], y0), __fsub_rn(pz[j], z0));
    }
    if (tid == 0) {
        centers[(b * NC + 0) * 3 + 0] = x0;
        centers[(b * NC + 0) * 3 + 1] = y0;
        centers[(b * NC + 0) * 3 + 2] = z0;
    }
    for (int i = 1; i < NC; i++) {
        // local argmax over 8 (ascending j => ascending global idx; strict >)
        float bv = mind[0]; int bn = tid;
        float bx = px[0], by = py[0], bz = pz[0];
#pragma unroll
        for (int j = 1; j < 8; j++)
            if (mind[j] > bv) { bv = mind[j]; bn = tid + 1024 * j;
                                bx = px[j]; by = py[j]; bz = pz[j]; }
        // wave-level 5-tuple argmax (first-index tie-break)
#pragma unroll
        for (int off = 32; off >= 1; off >>= 1) {
            float ov = __shfl_down(bv, off);
            int   on = __shfl_down(bn, off);
            float ox = __shfl_down(bx, off);
            float oy = __shfl_down(by, off);
            float oz = __shfl_down(bz, off);
            if (ov > bv || (ov == bv && on < bn)) { bv = ov; bn = on; bx = ox; by = oy; bz = oz; }
        }
        if ((tid & 63) == 0) {
            int w = tid >> 6;
            rv[w] = bv; ri[w] = bn; rx[w] = bx; ry[w] = by; rz[w] = bz;
        }
        __syncthreads();                               // A
        if (tid < 64) {                                // wave 0 reduces 16 partials
            float v = (tid < 16) ? rv[tid] : -MYFLT_MAX;
            int   n = (tid < 16) ? ri[tid] : 0x7fffffff;
            float x = (tid < 16) ? rx[tid] : 0.f;
            float y = (tid < 16) ? ry[tid] : 0.f;
            float z = (tid < 16) ? rz[tid] : 0.f;
#pragma unroll
            for (int off = 8; off >= 1; off >>= 1) {
                float ov = __shfl_down(v, off);
                int   on = __shfl_down(n, off);
                float ox = __shfl_down(x, off);
                float oy = __shfl_down(y, off);
                float oz = __shfl_down(z, off);
                if (ov > v || (ov == v && on < n)) { v = ov; n = on; x = ox; y = oy; z = oz; }
            }
            if (tid == 0) {
                winPt[0] = x; winPt[1] = y; winPt[2] = z;
                centers[(b * NC + i) * 3 + 0] = x;
                centers[(b * NC + i) * 3 + 1] = y;
                centers[(b * NC + i) * 3 + 2] = z;
            }
        }
        __syncthreads();                               // B
        const float cx = winPt[0], cy = winPt[1], cz = winPt[2];
#pragma unroll
        for (int j = 0; j < 8; j++) {
            float d = sq3(__fsub_rn(px[j], cx), __fsub_rn(py[j], cy), __fsub_rn(pz[j], cz));
            mind[j] = fminf(mind[j], d);
        }
    }
}

// ---------------------------------------------------------------- kNN: scale (+optional sel/cmean)
template<bool F32>
__global__ __launch_bounds__(256) void knn_kernel(
        const void* __restrict__ data, const int* __restrict__ perm,
        const float* __restrict__ centers, const unsigned int* __restrict__ flagp,
        unsigned int* __restrict__ scale_bits,
        int* __restrict__ selp, float* __restrict__ cmp) {
    __shared__ float dist[NN];
    __shared__ float rv4[4];
    __shared__ int   ri4[4];
    __shared__ int   winbuf;
    __shared__ int   sel[NP];
    if ((flagp[0] != 0u) != F32) return;
    const int m = blockIdx.x, b = m >> 8, c = m & 255, tid = threadIdx.x;
    const int ci = perm[c];
    const float cx = centers[((size_t)b * NC + ci) * 3 + 0];
    const float cy = centers[((size_t)b * NC + ci) * 3 + 1];
    const float cz = centers[((size_t)b * NC + ci) * 3 + 2];
    const float cn2 = sq3(cx, cy, cz);
    const size_t base = (size_t)b * 3 * NN;

    float bv = MYFLT_MAX; int bn = tid;
#pragma unroll 4
    for (int j = 0; j < 32; j++) {
        int n = tid + 256 * j;
        float x = LD<F32>(data, base + n);
        float y = LD<F32>(data, base + NN + n);
        float z = LD<F32>(data, base + 2 * NN + n);
        float pn2 = sq3(x, y, z);
        float dot = __fadd_rn(__fadd_rn(__fmul_rn(cx, x), __fmul_rn(cy, y)), __fmul_rn(cz, z));
        float d = __fsub_rn(__fadd_rn(cn2, pn2), __fmul_rn(2.0f, dot));
        dist[n] = d;
        if (d < bv) { bv = d; bn = n; }
    }
    for (int r = 0; r < NP; r++) {
        float v = bv; int n = bn;
#pragma unroll
        for (int off = 32; off >= 1; off >>= 1) {
            float ov = __shfl_down(v, off);
            int   on = __shfl_down(n, off);
            if (ov < v || (ov == v && on < n)) { v = ov; n = on; }
        }
        if ((tid & 63) == 0) { rv4[tid >> 6] = v; ri4[tid >> 6] = n; }
        __syncthreads();
        if (tid == 0) {
            float cv = rv4[0]; int cn = ri4[0];
#pragma unroll
            for (int w = 1; w < 4; w++)
                if (rv4[w] < cv || (rv4[w] == cv && ri4[w] < cn)) { cv = rv4[w]; cn = ri4[w]; }
            if ((unsigned)cn >= NN) cn = 0;
            winbuf = cn; sel[r] = cn;
        }
        __syncthreads();
        const int g = winbuf;
        if ((g & 255) == tid) {
            dist[g] = MYFLT_MAX;
            bv = MYFLT_MAX; bn = tid;
#pragma unroll 4
            for (int j = 0; j < 32; j++) {
                int nn2 = tid + 256 * j;
                float v2 = dist[nn2];
                if (v2 < bv) { bv = v2; bn = nn2; }
            }
        }
    }
    __syncthreads();
    if (tid < 32) {
        const int g = sel[tid];
        if (selp) selp[(size_t)m * 32 + tid] = g;
        float x = LD<F32>(data, base + g);
        float y = LD<F32>(data, base + NN + g);
        float z = LD<F32>(data, base + 2 * NN + g);
        float sx = x, sy = y, sz = z;
#pragma unroll
        for (int msk = 16; msk >= 1; msk >>= 1) {
            sx += __shfl_xor(sx, msk);
            sy += __shfl_xor(sy, msk);
            sz += __shfl_xor(sz, msk);
        }
        float mx = sx / 32.0f, my = sy / 32.0f, mz = sz / 32.0f;
        if (cmp && tid == 0) {
            cmp[(size_t)m * 3 + 0] = mx;
            cmp[(size_t)m * 3 + 1] = my;
            cmp[(size_t)m * 3 + 2] = mz;
        }
        float lx = x - mx, ly = y - my, lz = z - mz;
        float n2 = sq3(lx, ly, lz);
#pragma unroll
        for (int msk = 16; msk >= 1; msk >>= 1)
            n2 = fmaxf(n2, __shfl_xor(n2, msk));
        if (tid == 0) atomicMax(scale_bits, __float_as_uint(n2));
    }
}

// ---------------------------------------------------------------- scale
__global__ void finalize_kernel(const unsigned int* scale_bits, float* scale_v) {
    scale_v[0] = sqrtf(__uint_as_float(scale_bits[0]));
}

// ================================================================ MFMA encdec (big-ws path)
// A-frag write helper: element (m=p, k=c) of a [32 x K] A matrix, 16x16x32 tiles
__device__ __forceinline__ int afrag_idx(int p, int c) {
    int ks = c >> 5, mt = p >> 4;
    int lane = (p & 15) + 16 * ((c & 31) >> 3);
    return ((ks * 2 + mt) * 64 + lane) * 8 + (c & 7);
}

template<bool F32>
__global__ __launch_bounds__(256) void encdec_mfma(
        const void* __restrict__ data, const int* __restrict__ selp,
        const float* __restrict__ cmp, const float* __restrict__ scale_p,
        const unsigned int* __restrict__ flagp, const void* __restrict__ gridw,
        const void* __restrict__ We1, const void* __restrict__ be1,
        const unsigned short* __restrict__ We2_sw, const void* __restrict__ be2,
        const void* __restrict__ Wf1a, const unsigned int* __restrict__ p1,
        const void* __restrict__ bf1a,
        const unsigned short* __restrict__ Wf1b_sw, const void* __restrict__ bf1b,
        const void* __restrict__ Wf1c, const void* __restrict__ bf1c,
        const void* __restrict__ Wf2a, const unsigned int* __restrict__ p2,
        const void* __restrict__ bf2a,
        const unsigned short* __restrict__ Wf2b_sw, const void* __restrict__ bf2b,
        const void* __restrict__ Wf2c, const void* __restrict__ bf2c,
        void* __restrict__ out) {
    __shared__ unsigned short afrag[8192];   // 16 KB A-fragments (bf16)
    __shared__ float g2s[32 * 132];          // 16.9 KB [p][j] (+pad)
    __shared__ float code[256];
    __shared__ float xb[96];
    __shared__ float fb[96];
    __shared__ float gridb[64];
    if ((flagp[0] != 0u) != F32) return;
    const int m = blockIdx.x, b = m >> 8, tid = threadIdx.x;
    const int wv = tid >> 6, lane = tid & 63;
    const float scale = scale_p[0];
    const size_t base = (size_t)b * 3 * NN;
    if (tid < 64) gridb[tid] = LD<F32>(gridw, tid);
    if (tid < 32) {
        const int g = selp[(size_t)m * 32 + tid];
        xb[tid * 3 + 0] = (LD<F32>(data, base + g)          - cmp[(size_t)m * 3 + 0]) / scale;
        xb[tid * 3 + 1] = (LD<F32>(data, base + NN + g)     - cmp[(size_t)m * 3 + 1]) / scale;
        xb[tid * 3 + 2] = (LD<F32>(data, base + 2 * NN + g) - cmp[(size_t)m * 3 + 2]) / scale;
    }
    __syncthreads();
    // ---- E2: h1 = relu(x@We1+be1) -> afrag (A of [32p x 128k]) ----
    for (int o = tid; o < 4096; o += 256) {
        int p = o >> 7, ch = o & 127;
        float v = xb[p * 3 + 0] * LD<F32>(We1, ch) + xb[p * 3 + 1] * LD<F32>(We1, 128 + ch)
                + xb[p * 3 + 2] * LD<F32>(We1, 256 + ch) + LD<F32>(be1, ch);
        afrag[afrag_idx(p, ch)] = f2b(fmaxf(v, 0.0f));
    }
    __syncthreads();
    // ---- E3: code = relu(max_p(h1@We2) + be2) via MFMA ----
    {
        f32x4 acc[2][4];
#pragma unroll
        for (int a = 0; a < 2; a++)
#pragma unroll
            for (int t = 0; t < 4; t++) acc[a][t] = (f32x4){0.f, 0.f, 0.f, 0.f};
#pragma unroll
        for (int ks = 0; ks < 4; ks++) {
            short8 a0 = *(const short8*)&afrag[((ks * 2 + 0) * 64 + lane) * 8];
            short8 a1 = *(const short8*)&afrag[((ks * 2 + 1) * 64 + lane) * 8];
#pragma unroll
            for (int nt = 0; nt < 4; nt++) {
                short8 bf = *(const short8*)&We2_sw[((size_t)((4 * wv + nt) * 4 + ks) * 64 + lane) * 8];
                acc[0][nt] = __builtin_amdgcn_mfma_f32_16x16x32_bf16(a0, bf, acc[0][nt], 0, 0, 0);
                acc[1][nt] = __builtin_amdgcn_mfma_f32_16x16x32_bf16(a1, bf, acc[1][nt], 0, 0, 0);
            }
        }
#pragma unroll
        for (int nt = 0; nt < 4; nt++) {
            float mx = acc[0][nt][0];
#pragma unroll
            for (int r = 1; r < 4; r++) mx = fmaxf(mx, acc[0][nt][r]);
#pragma unroll
            for (int r = 0; r < 4; r++) mx = fmaxf(mx, acc[1][nt][r]);
            mx = fmaxf(mx, __shfl_xor(mx, 16));
            mx = fmaxf(mx, __shfl_xor(mx, 32));
            int n = 64 * wv + nt * 16 + (lane & 15);
            if (lane < 16) code[n] = fmaxf(mx + LD<F32>(be2, n), 0.0f);
        }
    }
    __syncthreads();
    // ---- D1: g1 = relu(code@Wf1a + bf1a + grid terms) -> afrag ----
    {
        float a0 = 0.f, a1 = 0.f;
#pragma unroll 8
        for (int k2 = 0; k2 < 128; k2++) {
            unsigned u = p1[k2 * 256 + tid];
            a0 = fmaf(code[2 * k2],     b2f((unsigned short)(u & 0xffffu)), a0);
            a1 = fmaf(code[2 * k2 + 1], b2f((unsigned short)(u >> 16)), a1);
        }
        float base1 = a0 + a1 + LD<F32>(bf1a, tid);
        float wu = LD<F32>(Wf1a, 65536 + tid);
        float wvv = LD<F32>(Wf1a, 65792 + tid);
#pragma unroll 8
        for (int p = 0; p < 32; p++) {
            float v = base1 + gridb[2 * p] * wu + gridb[2 * p + 1] * wvv;
            afrag[afrag_idx(p, tid)] = f2b(fmaxf(v, 0.0f));
        }
    }
    __syncthreads();
    // ---- D2: g2 = relu(g1@Wf1b + bf1b) via MFMA -> g2s ----
    {
        f32x4 acc[2][2];
#pragma unroll
        for (int a = 0; a < 2; a++)
#pragma unroll
            for (int t = 0; t < 2; t++) acc[a][t] = (f32x4){0.f, 0.f, 0.f, 0.f};
#pragma unroll
        for (int ks = 0; ks < 8; ks++) {
            short8 a0 = *(const short8*)&afrag[((ks * 2 + 0) * 64 + lane) * 8];
            short8 a1 = *(const short8*)&afrag[((ks * 2 + 1) * 64 + lane) * 8];
#pragma unroll
            for (int nt = 0; nt < 2; nt++) {
                short8 bf = *(const short8*)&Wf1b_sw[((size_t)((2 * wv + nt) * 8 + ks) * 64 + lane) * 8];
                acc[0][nt] = __builtin_amdgcn_mfma_f32_16x16x32_bf16(a0, bf, acc[0][nt], 0, 0, 0);
                acc[1][nt] = __builtin_amdgcn_mfma_f32_16x16x32_bf16(a1, bf, acc[1][nt], 0, 0, 0);
            }
        }
#pragma unroll
        for (int nt = 0; nt < 2; nt++) {
            int n = 32 * wv + nt * 16 + (lane & 15);
            float bb = LD<F32>(bf1b, n);
#pragma unroll
            for (int mt = 0; mt < 2; mt++)
#pragma unroll
                for (int r = 0; r < 4; r++) {
                    int mm = mt * 16 + (lane >> 4) * 4 + r;
                    g2s[mm * 132 + n] = fmaxf(acc[mt][nt][r] + bb, 0.0f);
                }
        }
    }
    __syncthreads();
    // ---- D3: fb = g2@Wf1c + bf1c ----
    if (tid < 96) {
        int p = tid / 3, e = tid % 3;
        float acc = 0.0f;
#pragma unroll 8
        for (int k = 0; k < 128; k++)
            acc = fmaf(g2s[p * 132 + k], LD<F32>(Wf1c, k * 3 + e), acc);
        fb[tid] = acc + LD<F32>(bf1c, e);
    }
    __syncthreads();
    // ---- D4: g1' = relu(code@Wf2a + bf2a + f terms) -> afrag ----
    {
        float a0 = 0.f, a1 = 0.f;
#pragma unroll 8
        for (int k2 = 0; k2 < 128; k2++) {
            unsigned u = p2[k2 * 256 + tid];
            a0 = fmaf(code[2 * k2],     b2f((unsigned short)(u & 0xffffu)), a0);
            a1 = fmaf(code[2 * k2 + 1], b2f((unsigned short)(u >> 16)), a1);
        }
        float base2 = a0 + a1 + LD<F32>(bf2a, tid);
        float w0 = LD<F32>(Wf2a, 65536 + tid);
        float w1 = LD<F32>(Wf2a, 65792 + tid);
        float w2 = LD<F32>(Wf2a, 66048 + tid);
#pragma unroll 8
        for (int p = 0; p < 32; p++) {
            float v = base2 + fb[p * 3] * w0 + fb[p * 3 + 1] * w1 + fb[p * 3 + 2] * w2;
            afrag[afrag_idx(p, tid)] = f2b(fmaxf(v, 0.0f));
        }
    }
    __syncthreads();
    // ---- D5: g2' = relu(g1'@Wf2b + bf2b) via MFMA -> g2s ----
    {
        f32x4 acc[2][2];
#pragma unroll
        for (int a = 0; a < 2; a++)
#pragma unroll
            for (int t = 0; t < 2; t++) acc[a][t] = (f32x4){0.f, 0.f, 0.f, 0.f};
#pragma unroll
        for (int ks = 0; ks < 8; ks++) {
            short8 a0 = *(const short8*)&afrag[((ks * 2 + 0) * 64 + lane) * 8];
            short8 a1 = *(const short8*)&afrag[((ks * 2 + 1) * 64 + lane) * 8];
#pragma unroll
            for (int nt = 0; nt < 2; nt++) {
                short8 bf = *(const short8*)&Wf2b_sw[((size_t)((2 * wv + nt) * 8 + ks) * 64 + lane) * 8];
                acc[0][nt] = __builtin_amdgcn_mfma_f32_16x16x32_bf16(a0, bf, acc[0][nt], 0, 0, 0);
                acc[1][nt] = __builtin_amdgcn_mfma_f32_16x16x32_bf16(a1, bf, acc[1][nt], 0, 0, 0);
            }
        }
#pragma unroll
        for (int nt = 0; nt < 2; nt++) {
            int n = 32 * wv + nt * 16 + (lane & 15);
            float bb = LD<F32>(bf2b, n);
#pragma unroll
            for (int mt = 0; mt < 2; mt++)
#pragma unroll
                for (int r = 0; r < 4; r++) {
                    int mm = mt * 16 + (lane >> 4) * 4 + r;
                    g2s[mm * 132 + n] = fmaxf(acc[mt][nt][r] + bb, 0.0f);
                }
        }
    }
    __syncthreads();
    // ---- D6: out = (g2'@Wf2c + bf2c)*scale + cmean ----
    if (tid < 96) {
        int p = tid / 3, e = tid % 3;
        float acc = 0.0f;
#pragma unroll 8
        for (int k = 0; k < 128; k++)
            acc = fmaf(g2s[p * 132 + k], LD<F32>(Wf2c, k * 3 + e), acc);
        float v = (acc + LD<F32>(bf2c, e)) * scale + cmp[(size_t)m * 3 + e];
        size_t oi = (size_t)m * 96 + tid;
        if (F32) ((float*)out)[oi] = v;
        else     ((unsigned short*)out)[oi] = f2b(v);
    }
}

// ================================================================ fallback fused encdec (R4)
template<bool F32>
__global__ __launch_bounds__(256) void encdec_fused(
        const void* __restrict__ data,
        const int* __restrict__ perm, const float* __restrict__ centers,
        const float* __restrict__ scale_p, const unsigned int* __restrict__ flagp,
        const void* __restrict__ gridw,
        const void* __restrict__ We1, const void* __restrict__ be1,
        const void* __restrict__ We2, const void* __restrict__ be2,
        const void* __restrict__ Wf1a, const void* __restrict__ bf1a,
        const void* __restrict__ Wf1b, const void* __restrict__ bf1b,
        const void* __restrict__ Wf1c, const void* __restrict__ bf1c,
        const void* __restrict__ Wf2a, const void* __restrict__ bf2a,
        const void* __restrict__ Wf2b, const void* __restrict__ bf2b,
        const void* __restrict__ Wf2c, const void* __restrict__ bf2c,
        void* __restrict__ out) {
    __shared__ float bigA[256 * 36];
    __shared__ float bigB[128 * 36];
    __shared__ float code[256];
    __shared__ float xb[96];
    __shared__ float fb[96];
    __shared__ float gridb[64];
    __shared__ float meansh[4];
    __shared__ float rv4[4];
    __shared__ int   ri4[4];
    __shared__ int   winbuf;
    __shared__ int   sel[NP];
    if ((flagp[0] != 0u) != F32) return;
    const int m = (NB * NC - 1) - blockIdx.x;
    const int b = m >> 8, c = m & 255, tid = threadIdx.x;
    const float scale = scale_p[0];
    const int ci = perm[c];
    const float cx = centers[((size_t)b * NC + ci) * 3 + 0];
    const float cy = centers[((size_t)b * NC + ci) * 3 + 1];
    const float cz = centers[((size_t)b * NC + ci) * 3 + 2];
    const float cn2 = sq3(cx, cy, cz);
    const size_t base = (size_t)b * 3 * NN;
    if (tid < 64) gridb[tid] = LD<F32>(gridw, tid);
    float* dist = bigA;
    float bv = MYFLT_MAX; int bn = tid;
#pragma unroll 4
    for (int j = 0; j < 32; j++) {
        int n = tid + 256 * j;
        float x = LD<F32>(data, base + n);
        float y = LD<F32>(data, base + NN + n);
        float z = LD<F32>(data, base + 2 * NN + n);
        float pn2 = sq3(x, y, z);
        float dot = __fadd_rn(__fadd_rn(__fmul_rn(cx, x), __fmul_rn(cy, y)), __fmul_rn(cz, z));
        float d = __fsub_rn(__fadd_rn(cn2, pn2), __fmul_rn(2.0f, dot));
        dist[n] = d;
        if (d < bv) { bv = d; bn = n; }
    }
    for (int r = 0; r < NP; r++) {
        float v = bv; int n = bn;
#pragma unroll
        for (int off = 32; off >= 1; off >>= 1) {
            float ov = __shfl_down(v, off);
            int   on = __shfl_down(n, off);
            if (ov < v || (ov == v && on < n)) { v = ov; n = on; }
        }
        if ((tid & 63) == 0) { rv4[tid >> 6] = v; ri4[tid >> 6] = n; }
        __syncthreads();
        if (tid == 0) {
            float cv = rv4[0]; int cn = ri4[0];
#pragma unroll
            for (int w = 1; w < 4; w++)
                if (rv4[w] < cv || (rv4[w] == cv && ri4[w] < cn)) { cv = rv4[w]; cn = ri4[w]; }
            if ((unsigned)cn >= NN) cn = 0;
            winbuf = cn; sel[r] = cn;
        }
        __syncthreads();
        const int g = winbuf;
        if ((g & 255) == tid) {
            dist[g] = MYFLT_MAX;
            bv = MYFLT_MAX; bn = tid;
#pragma unroll 4
            for (int j = 0; j < 32; j++) {
                int nn2 = tid + 256 * j;
                float v2 = dist[nn2];
                if (v2 < bv) { bv = v2; bn = nn2; }
            }
        }
    }
    __syncthreads();
    if (tid < 32) {
        const int g = sel[tid];
        float x = LD<F32>(data, base + g);
        float y = LD<F32>(data, base + NN + g);
        float z = LD<F32>(data, base + 2 * NN + g);
        float sx = x, sy = y, sz = z;
#pragma unroll
        for (int msk = 16; msk >= 1; msk >>= 1) {
            sx += __shfl_xor(sx, msk);
            sy += __shfl_xor(sy, msk);
            sz += __shfl_xor(sz, msk);
        }
        float mx = sx / 32.0f, my = sy / 32.0f, mz = sz / 32.0f;
        xb[tid * 3 + 0] = (x - mx) / scale;
        xb[tid * 3 + 1] = (y - my) / scale;
        xb[tid * 3 + 2] = (z - mz) / scale;
        if (tid == 0) { meansh[0] = mx; meansh[1] = my; meansh[2] = mz; }
    }
    __syncthreads();
    for (int o = tid; o < 4096; o += 256) {
        int p = o >> 7, i = o & 127;
        float v = xb[p * 3 + 0] * LD<F32>(We1, i) + xb[p * 3 + 1] * LD<F32>(We1, 128 + i)
                + xb[p * 3 + 2] * LD<F32>(We1, 256 + i) + LD<F32>(be1, i);
        bigB[i * 36 + p] = fmaxf(v, 0.0f);
    }
    __syncthreads();
    {
        float acc[32];
#pragma unroll
        for (int p = 0; p < 32; p++) acc[p] = 0.0f;
        for (int k = 0; k < 128; k++) {
            float w = LD<F32>(We2, k * 256 + tid);
            const float4* hp = (const float4*)&bigB[k * 36];
#pragma unroll
            for (int q = 0; q < 8; q++) {
                float4 h4 = hp[q];
                acc[q * 4 + 0] = fmaf(h4.x, w, acc[q * 4 + 0]);
                acc[q * 4 + 1] = fmaf(h4.y, w, acc[q * 4 + 1]);
                acc[q * 4 + 2] = fmaf(h4.z, w, acc[q * 4 + 2]);
                acc[q * 4 + 3] = fmaf(h4.w, w, acc[q * 4 + 3]);
            }
        }
        float mx = acc[0];
#pragma unroll
        for (int p = 1; p < 32; p++) mx = fmaxf(mx, acc[p]);
        code[tid] = fmaxf(mx + LD<F32>(be2, tid), 0.0f);
    }
    __syncthreads();
    {
        float a0 = 0.f, a1 = 0.f, a2 = 0.f, a3 = 0.f;
        for (int k = 0; k < 256; k += 4) {
            a0 = fmaf(code[k + 0], LD<F32>(Wf1a, (k + 0) * 256 + tid), a0);
            a1 = fmaf(code[k + 1], LD<F32>(Wf1a, (k + 1) * 256 + tid), a1);
            a2 = fmaf(code[k + 2], LD<F32>(Wf1a, (k + 2) * 256 + tid), a2);
            a3 = fmaf(code[k + 3], LD<F32>(Wf1a, (k + 3) * 256 + tid), a3);
        }
        float base1 = ((a0 + a1) + (a2 + a3)) + LD<F32>(bf1a, tid);
        float wu = LD<F32>(Wf1a, 65536 + tid);
        float wvv = LD<F32>(Wf1a, 65792 + tid);
#pragma unroll 8
        for (int p = 0; p < 32; p++) {
            float v = base1 + gridb[2 * p] * wu + gridb[2 * p + 1] * wvv;
            bigA[tid * 36 + p] = fmaxf(v, 0.0f);
        }
    }
    __syncthreads();
    {
        int j = tid & 127, ph = tid >> 7;
        float acc[16];
#pragma unroll
        for (int q = 0; q < 16; q++) acc[q] = 0.0f;
        for (int k = 0; k < 256; k++) {
            float w = LD<F32>(Wf1b, k * 128 + j);
            const float4* gp = (const float4*)&bigA[k * 36 + ph * 16];
            float4 h0 = gp[0], h1 = gp[1], h2 = gp[2], h3 = gp[3];
            acc[0] = fmaf(h0.x, w, acc[0]);   acc[1] = fmaf(h0.y, w, acc[1]);
            acc[2] = fmaf(h0.z, w, acc[2]);   acc[3] = fmaf(h0.w, w, acc[3]);
            acc[4] = fmaf(h1.x, w, acc[4]);   acc[5] = fmaf(h1.y, w, acc[5]);
            acc[6] = fmaf(h1.z, w, acc[6]);   acc[7] = fmaf(h1.w, w, acc[7]);
            acc[8] = fmaf(h2.x, w, acc[8]);   acc[9] = fmaf(h2.y, w, acc[9]);
            acc[10] = fmaf(h2.z, w, acc[10]); acc[11] = fmaf(h2.w, w, acc[11]);
            acc[12] = fmaf(h3.x, w, acc[12]); acc[13] = fmaf(h3.y, w, acc[13]);
            acc[14] = fmaf(h3.z, w, acc[14]); acc[15] = fmaf(h3.w, w, acc[15]);
        }
        float bb = LD<F32>(bf1b, j);
#pragma unroll
        for (int q = 0; q < 16; q++)
            bigB[j * 36 + ph * 16 + q] = fmaxf(acc[q] + bb, 0.0f);
    }
    __syncthreads();
    if (tid < 96) {
        int p = tid / 3, e = tid % 3;
        float acc = 0.0f;
        for (int k = 0; k < 128; k++)
            acc = fmaf(bigB[k * 36 + p], LD<F32>(Wf1c, k * 3 + e), acc);
        fb[tid] = acc + LD<F32>(bf1c, e);
    }
    __syncthreads();
    {
        float a0 = 0.f, a1 = 0.f, a2 = 0.f, a3 = 0.f;
        for (int k = 0; k < 256; k += 4) {
            a0 = fmaf(code[k + 0], LD<F32>(Wf2a, (k + 0) * 256 + tid), a0);
            a1 = fmaf(code[k + 1], LD<F32>(Wf2a, (k + 1) * 256 + tid), a1);
            a2 = fmaf(code[k + 2], LD<F32>(Wf2a, (k + 2) * 256 + tid), a2);
            a3 = fmaf(code[k + 3], LD<F32>(Wf2a, (k + 3) * 256 + tid), a3);
        }
        float base2 = ((a0 + a1) + (a2 + a3)) + LD<F32>(bf2a, tid);
        float w0 = LD<F32>(Wf2a, 65536 + tid);
        float w1 = LD<F32>(Wf2a, 65792 + tid);
        float w2 = LD<F32>(Wf2a, 66048 + tid);
#pragma unroll 8
        for (int p = 0; p < 32; p++) {
            float v = base2 + fb[p * 3] * w0 + fb[p * 3 + 1] * w1 + fb[p * 3 + 2] * w2;
            bigA[tid * 36 + p] = fmaxf(v, 0.0f);
        }
    }
    __syncthreads();
    {
        int j = tid & 127, ph = tid >> 7;
        float acc[16];
#pragma unroll
        for (int q = 0; q < 16; q++) acc[q] = 0.0f;
        for (int k = 0; k < 256; k++) {
            float w = LD<F32>(Wf2b, k * 128 + j);
            const float4* gp = (const float4*)&bigA[k * 36 + ph * 16];
            float4 h0 = gp[0], h1 = gp[1], h2 = gp[2], h3 = gp[3];
            acc[0] = fmaf(h0.x, w, acc[0]);   acc[1] = fmaf(h0.y, w, acc[1]);
            acc[2] = fmaf(h0.z, w, acc[2]);   acc[3] = fmaf(h0.w, w, acc[3]);
            acc[4] = fmaf(h1.x, w, acc[4]);   acc[5] = fmaf(h1.y, w, acc[5]);
            acc[6] = fmaf(h1.z, w, acc[6]);   acc[7] = fmaf(h1.w, w, acc[7]);
            acc[8] = fmaf(h2.x, w, acc[8]);   acc[9] = fmaf(h2.y, w, acc[9]);
            acc[10] = fmaf(h2.z, w, acc[10]); acc[11] = fmaf(h2.w, w, acc[11]);
            acc[12] = fmaf(h3.x, w, acc[12]); acc[13] = fmaf(h3.y, w, acc[13]);
            acc[14] = fmaf(h3.z, w, acc[14]); acc[15] = fmaf(h3.w, w, acc[15]);
        }
        float bb = LD<F32>(bf2b, j);
#pragma unroll
        for (int q = 0; q < 16; q++)
            bigB[j * 36 + ph * 16 + q] = fmaxf(acc[q] + bb, 0.0f);
    }
    __syncthreads();
    if (tid < 96) {
        int p = tid / 3, e = tid % 3;
        float acc = 0.0f;
        for (int k = 0; k < 128; k++)
            acc = fmaf(bigB[k * 36 + p], LD<F32>(Wf2c, k * 3 + e), acc);
        float v = (acc + LD<F32>(bf2c, e)) * scale + meansh[e];
        size_t oi = (size_t)m * 96 + tid;
        if (F32) ((float*)out)[oi] = v;
        else     ((unsigned short*)out)[oi] = f2b(v);
    }
}

extern "C" void kernel_launch(void* const* d_in, const int* in_sizes, int n_in,
                              void* d_out, int out_size, void* d_ws, size_t ws_size,
                              hipStream_t stream) {
    const void* data = d_in[0];
    const int* perm  = (const int*)d_in[1];
    const void* grid = d_in[2];
    const void *We1 = d_in[3], *be1 = d_in[4], *We2 = d_in[5], *be2 = d_in[6];
    const void *Wf1a = d_in[7], *bf1a = d_in[8], *Wf1b = d_in[9], *bf1b = d_in[10];
    const void *Wf1c = d_in[11], *bf1c = d_in[12];
    const void *Wf2a = d_in[13], *bf2a = d_in[14], *Wf2b = d_in[15], *bf2b = d_in[16];
    const void *Wf2c = d_in[17], *bf2c = d_in[18];

    if (ws_size >= (size_t)4 * 1024 * 1024) {
        // ---------- big-ws MFMA path ----------
        float* ws = (float*)d_ws;
        unsigned int* wbase   = (unsigned int*)ws;     // [0]=scale_bits,[2]=flag
        float*        scale_v = ws + 1;
        unsigned int* flagp   = wbase + 2;
        float*        centers = ws + 4;                // 24576
        float*        cmeanp  = ws + 24580;            // 24576
        int*          selp    = (int*)(ws + 49156);    // 262144
        unsigned short* We2_sw  = (unsigned short*)(ws + 311304);  // 32768 bf16
        unsigned short* Wf1b_sw = (unsigned short*)(ws + 327688);
        unsigned short* Wf2b_sw = (unsigned short*)(ws + 344072);
        unsigned int*   p1      = (unsigned int*)(ws + 360456);    // 32768 u32
        unsigned int*   p2      = (unsigned int*)(ws + 393224);

        init_kernel<<<1, 1, 0, stream>>>(wbase);
        detect_kernel<<<256, 256, 0, stream>>>(data, flagp);
        prep_kernel<false><<<640, 256, 0, stream>>>(We2, Wf1b, Wf2b, Wf1a, Wf2a, flagp,
                                                    We2_sw, Wf1b_sw, Wf2b_sw, p1, p2);
        prep_kernel<true ><<<640, 256, 0, stream>>>(We2, Wf1b, Wf2b, Wf1a, Wf2a, flagp,
                                                    We2_sw, Wf1b_sw, Wf2b_sw, p1, p2);
        fps_kernel<false><<<NB, 1024, 0, stream>>>(data, flagp, centers);
        fps_kernel<true ><<<NB, 1024, 0, stream>>>(data, flagp, centers);
        knn_kernel<false><<<NB * NC, 256, 0, stream>>>(data, perm, centers, flagp, wbase, selp, cmeanp);
        knn_kernel<true ><<<NB * NC, 256, 0, stream>>>(data, perm, centers, flagp, wbase, selp, cmeanp);
        finalize_kernel<<<1, 1, 0, stream>>>(wbase, scale_v);
        encdec_mfma<false><<<NB * NC, 256, 0, stream>>>(data, selp, cmeanp, scale_v, flagp, grid,
                We1, be1, We2_sw, be2, Wf1a, p1, bf1a, Wf1b_sw, bf1b, Wf1c, bf1c,
                Wf2a, p2, bf2a, Wf2b_sw, bf2b, Wf2c, bf2c, d_out);
        encdec_mfma<true ><<<NB * NC, 256, 0, stream>>>(data, selp, cmeanp, scale_v, flagp, grid,
                We1, be1, We2_sw, be2, Wf1a, p1, bf1a, Wf1b_sw, bf1b, Wf1c, bf1c,
                Wf2a, p2, bf2a, Wf2b_sw, bf2b, Wf2c, bf2c, d_out);
    } else {
        // ---------- fallback: R4 path verbatim ----------
        float* ov = (ws_size >= (size_t)131072) ? (float*)d_ws : (float*)d_out;
        unsigned int* wbase   = (unsigned int*)ov;
        float*        scale_v = ov + 1;
        unsigned int* flagp   = wbase + 2;
        float*        centers = ov + 4;

        init_kernel<<<1, 1, 0, stream>>>(wbase);
        detect_kernel<<<256, 256, 0, stream>>>(data, flagp);
        fps_kernel<false><<<NB, 1024, 0, stream>>>(data, flagp, centers);
        fps_kernel<true ><<<NB, 1024, 0, stream>>>(data, flagp, centers);
        knn_kernel<false><<<NB * NC, 256, 0, stream>>>(data, perm, centers, flagp, wbase, nullptr, nullptr);
        knn_kernel<true ><<<NB * NC, 256, 0, stream>>>(data, perm, centers, flagp, wbase, nullptr, nullptr);
        finalize_kernel<<<1, 1, 0, stream>>>(wbase, scale_v);
        encdec_fused<false><<<NB * NC, 256, 0, stream>>>(data, perm, centers, scale_v, flagp,
                grid, We1, be1, We2, be2, Wf1a, bf1a, Wf1b, bf1b, Wf1c, bf1c,
                Wf2a, bf2a, Wf2b, bf2b, Wf2c, bf2c, d_out);
        encdec_fused<true ><<<NB * NC, 256, 0, stream>>>(data, perm, centers, scale_v, flagp,
                grid, We1, be1, We2, be2, Wf1a, bf1a, Wf1b, bf1b, Wf1c, bf1c,
                Wf2a, bf2a, Wf2b, bf2b, Wf2c, bf2c, d_out);
    }
}

// Round 7
// 1204.955 us; speedup vs baseline: 2.6054x; 1.1835x over previous
//
#include <hip/hip_runtime.h>

#define NB 32
#define NN 8192
#define NC 256
#define NP 32
#define MYFLT_MAX 3.402823466e+38f

typedef __attribute__((ext_vector_type(8))) short short8;
typedef __attribute__((ext_vector_type(4))) float f32x4;

__device__ __forceinline__ float b2f(unsigned short u) {
    return __uint_as_float(((unsigned)u) << 16);
}
__device__ __forceinline__ unsigned short f2b(float f) {
    unsigned u = __float_as_uint(f);
    unsigned r = u + 0x7fffu + ((u >> 16) & 1u);
    return (unsigned short)(r >> 16);
}
template<bool F32>
__device__ __forceinline__ float LD(const void* __restrict__ p, size_t i) {
    if (F32) return ((const float* __restrict__)p)[i];
    else     return b2f(((const unsigned short* __restrict__)p)[i]);
}
// exact f32, no FMA contraction, reference association ((x*x + y*y) + z*z)
__device__ __forceinline__ float sq3(float x, float y, float z) {
    return __fadd_rn(__fadd_rn(__fmul_rn(x, x), __fmul_rn(y, y)), __fmul_rn(z, z));
}

// 64-bit key argmax step over a DPP lane pattern. key=(hi,lo) with hi=dist
// bits (>=0), lo=~idx: max key == max dist, tie -> smallest idx. bound_ctrl
// gives 0 for invalid lanes; key 0 never wins (lo=~idx>0 for idx<2^32-1).
template<int CTRL>
__device__ __forceinline__ void dpp_max2(unsigned& hi, unsigned& lo) {
    unsigned nh = (unsigned)__builtin_amdgcn_update_dpp(0, (int)hi, CTRL, 0xF, 0xF, true);
    unsigned nl = (unsigned)__builtin_amdgcn_update_dpp(0, (int)lo, CTRL, 0xF, 0xF, true);
    if (nh > hi || (nh == hi && nl > lo)) { hi = nh; lo = nl; }
}

// ---------------------------------------------------------------- init
__global__ void init_kernel(unsigned int* w) {
    w[0] = 0u;   // scale_bits
    w[2] = 0u;   // dtype flag (0 = bf16, >0 = f32)
}

// ---------------------------------------------------------------- dtype probe
__global__ __launch_bounds__(256) void detect_kernel(
        const void* __restrict__ data, unsigned int* __restrict__ flag) {
    const unsigned short* u = (const unsigned short*)data;
    int t = blockIdx.x * 256 + threadIdx.x;
    unsigned cnt = 0;
    for (size_t i = (size_t)t * 2; i < 786432; i += 131072)
        if ((u[i] & 0x7F80u) == 0x7F80u) cnt++;
    if (cnt) atomicAdd(flag, cnt);
}

// ---------------------------------------------------------------- weight prep (bf16 swizzle into ws)
// B-frag layout for mfma_f32_16x16x32_bf16: lane=(n&15)+16*((k&31)>>3), j=k&7
__device__ __forceinline__ size_t bfrag_idx(int k, int n, int nks) {
    int nt = n >> 4, ks = k >> 5;
    int lane = (n & 15) + 16 * ((k & 31) >> 3);
    return ((size_t)(nt * nks + ks) * 64 + lane) * 8 + (k & 7);
}
template<bool F32>
__global__ __launch_bounds__(256) void prep_kernel(
        const void* __restrict__ We2, const void* __restrict__ Wf1b,
        const void* __restrict__ Wf2b, const void* __restrict__ Wf1a,
        const void* __restrict__ Wf2a, const unsigned int* __restrict__ flagp,
        unsigned short* __restrict__ We2_sw, unsigned short* __restrict__ Wf1b_sw,
        unsigned short* __restrict__ Wf2b_sw, unsigned int* __restrict__ p1,
        unsigned int* __restrict__ p2) {
    if ((flagp[0] != 0u) != F32) return;
    int i = blockIdx.x * 256 + threadIdx.x;          // 163840 total
    if (i < 32768) {                                  // We2 [128,256]
        int k = i >> 8, n = i & 255;
        We2_sw[bfrag_idx(k, n, 4)] = f2b(LD<F32>(We2, i));
    } else if (i < 65536) {                           // Wf1b [256,128]
        int j = i - 32768, k = j >> 7, n = j & 127;
        Wf1b_sw[bfrag_idx(k, n, 8)] = f2b(LD<F32>(Wf1b, j));
    } else if (i < 98304) {                           // Wf2b [256,128]
        int j = i - 65536, k = j >> 7, n = j & 127;
        Wf2b_sw[bfrag_idx(k, n, 8)] = f2b(LD<F32>(Wf2b, j));
    } else if (i < 131072) {                          // Wf1a rows 0..255 paired
        int j = i - 98304, k2 = j >> 8, c = j & 255;
        unsigned lo = f2b(LD<F32>(Wf1a, (size_t)(2 * k2) * 256 + c));
        unsigned hi = f2b(LD<F32>(Wf1a, (size_t)(2 * k2 + 1) * 256 + c));
        p1[j] = lo | (hi << 16);
    } else {                                          // Wf2a rows 0..255 paired
        int j = i - 131072, k2 = j >> 8, c = j & 255;
        unsigned lo = f2b(LD<F32>(Wf2a, (size_t)(2 * k2) * 256 + c));
        unsigned hi = f2b(LD<F32>(Wf2a, (size_t)(2 * k2 + 1) * 256 + c));
        p2[j] = lo | (hi << 16);
    }
}

// ---------------------------------------------------------------- FPS
// one block/batch; 1024 threads x 8 points in registers. Argmax via packed
// 64-bit keys reduced with DPP (VALU pipe, no ds_bpermute). Winner coords
// re-read from data (same-address wave load = L1 broadcast). 2 barriers/iter.
template<bool F32>
__global__ __launch_bounds__(1024) void fps_kernel(
        const void* __restrict__ data, const unsigned int* __restrict__ flagp,
        float* __restrict__ centers) {
    __shared__ unsigned rhi[16], rlo[16];
    __shared__ unsigned winlo_s;
    if ((flagp[0] != 0u) != F32) return;
    const int b = blockIdx.x, tid = threadIdx.x;
    const int lane = tid & 63;
    const size_t base = (size_t)b * 3 * NN;
    const float x0 = LD<F32>(data, base);
    const float y0 = LD<F32>(data, base + NN);
    const float z0 = LD<F32>(data, base + 2 * NN);
    float px[8], py[8], pz[8], mind[8];
#pragma unroll
    for (int j = 0; j < 8; j++) {
        int n = tid + 1024 * j;
        px[j] = LD<F32>(data, base + n);
        py[j] = LD<F32>(data, base + NN + n);
        pz[j] = LD<F32>(data, base + 2 * NN + n);
        mind[j] = sq3(__fsub_rn(px[j], x0), __fsub_rn(py[j], y0), __fsub_rn(pz[j], z0));
    }
    if (tid == 0) {
        centers[(b * NC + 0) * 3 + 0] = x0;
        centers[(b * NC + 0) * 3 + 1] = y0;
        centers[(b * NC + 0) * 3 + 2] = z0;
    }
    for (int i = 1; i < NC; i++) {
        // local argmax over 8 as packed key (tie -> smaller idx == larger ~idx)
        unsigned hi = __float_as_uint(mind[0]);
        unsigned lo = ~(unsigned)tid;
#pragma unroll
        for (int j = 1; j < 8; j++) {
            unsigned h2 = __float_as_uint(mind[j]);
            unsigned l2 = ~(unsigned)(tid + 1024 * j);
            if (h2 > hi || (h2 == hi && l2 > lo)) { hi = h2; lo = l2; }
        }
        // wave64 DPP argmax -> lane 63
        dpp_max2<0x111>(hi, lo);   // row_shr:1
        dpp_max2<0x112>(hi, lo);   // row_shr:2
        dpp_max2<0x114>(hi, lo);   // row_shr:4
        dpp_max2<0x118>(hi, lo);   // row_shr:8
        dpp_max2<0x142>(hi, lo);   // row_bcast:15
        dpp_max2<0x143>(hi, lo);   // row_bcast:31
        if (lane == 63) { rhi[tid >> 6] = hi; rlo[tid >> 6] = lo; }
        __syncthreads();                               // A
        if (tid < 64) {                                // wave 0: reduce 16 partials
            unsigned h = (tid < 16) ? rhi[tid] : 0u;
            unsigned l = (tid < 16) ? rlo[tid] : 0u;
            dpp_max2<0x111>(h, l);
            dpp_max2<0x112>(h, l);
            dpp_max2<0x114>(h, l);
            dpp_max2<0x118>(h, l);                     // lane 15 = block max
            if (tid == 15) winlo_s = l;
        }
        __syncthreads();                               // B
        const int g = (int)(~winlo_s);                 // winner index (always valid)
        const float cx = LD<F32>(data, base + g);      // same addr all lanes ->
        const float cy = LD<F32>(data, base + NN + g); //   L1 broadcast
        const float cz = LD<F32>(data, base + 2 * NN + g);
        if (tid == 0) {
            centers[(b * NC + i) * 3 + 0] = cx;
            centers[(b * NC + i) * 3 + 1] = cy;
            centers[(b * NC + i) * 3 + 2] = cz;
        }
#pragma unroll
        for (int j = 0; j < 8; j++) {
            float d = sq3(__fsub_rn(px[j], cx), __fsub_rn(py[j], cy), __fsub_rn(pz[j], cz));
            mind[j] = fminf(mind[j], d);
        }
    }
}

// ---------------------------------------------------------------- kNN: scale (+optional sel/cmean)
template<bool F32>
__global__ __launch_bounds__(256) void knn_kernel(
        const void* __restrict__ data, const int* __restrict__ perm,
        const float* __restrict__ centers, const unsigned int* __restrict__ flagp,
        unsigned int* __restrict__ scale_bits,
        int* __restrict__ selp, float* __restrict__ cmp) {
    __shared__ float dist[NN];
    __shared__ float rv4[4];
    __shared__ int   ri4[4];
    __shared__ int   winbuf;
    __shared__ int   sel[NP];
    if ((flagp[0] != 0u) != F32) return;
    const int m = blockIdx.x, b = m >> 8, c = m & 255, tid = threadIdx.x;
    const int ci = perm[c];
    const float cx = centers[((size_t)b * NC + ci) * 3 + 0];
    const float cy = centers[((size_t)b * NC + ci) * 3 + 1];
    const float cz = centers[((size_t)b * NC + ci) * 3 + 2];
    const float cn2 = sq3(cx, cy, cz);
    const size_t base = (size_t)b * 3 * NN;

    float bv = MYFLT_MAX; int bn = tid;
#pragma unroll 4
    for (int j = 0; j < 32; j++) {
        int n = tid + 256 * j;
        float x = LD<F32>(data, base + n);
        float y = LD<F32>(data, base + NN + n);
        float z = LD<F32>(data, base + 2 * NN + n);
        float pn2 = sq3(x, y, z);
        float dot = __fadd_rn(__fadd_rn(__fmul_rn(cx, x), __fmul_rn(cy, y)), __fmul_rn(cz, z));
        float d = __fsub_rn(__fadd_rn(cn2, pn2), __fmul_rn(2.0f, dot));
        dist[n] = d;
        if (d < bv) { bv = d; bn = n; }
    }
    for (int r = 0; r < NP; r++) {
        float v = bv; int n = bn;
#pragma unroll
        for (int off = 32; off >= 1; off >>= 1) {
            float ov = __shfl_down(v, off);
            int   on = __shfl_down(n, off);
            if (ov < v || (ov == v && on < n)) { v = ov; n = on; }
        }
        if ((tid & 63) == 0) { rv4[tid >> 6] = v; ri4[tid >> 6] = n; }
        __syncthreads();
        if (tid == 0) {
            float cv = rv4[0]; int cn = ri4[0];
#pragma unroll
            for (int w = 1; w < 4; w++)
                if (rv4[w] < cv || (rv4[w] == cv && ri4[w] < cn)) { cv = rv4[w]; cn = ri4[w]; }
            if ((unsigned)cn >= NN) cn = 0;
            winbuf = cn; sel[r] = cn;
        }
        __syncthreads();
        const int g = winbuf;
        if ((g & 255) == tid) {
            dist[g] = MYFLT_MAX;
            bv = MYFLT_MAX; bn = tid;
#pragma unroll 4
            for (int j = 0; j < 32; j++) {
                int nn2 = tid + 256 * j;
                float v2 = dist[nn2];
                if (v2 < bv) { bv = v2; bn = nn2; }
            }
        }
    }
    __syncthreads();
    if (tid < 32) {
        const int g = sel[tid];
        if (selp) selp[(size_t)m * 32 + tid] = g;
        float x = LD<F32>(data, base + g);
        float y = LD<F32>(data, base + NN + g);
        float z = LD<F32>(data, base + 2 * NN + g);
        float sx = x, sy = y, sz = z;
#pragma unroll
        for (int msk = 16; msk >= 1; msk >>= 1) {
            sx += __shfl_xor(sx, msk);
            sy += __shfl_xor(sy, msk);
            sz += __shfl_xor(sz, msk);
        }
        float mx = sx / 32.0f, my = sy / 32.0f, mz = sz / 32.0f;
        if (cmp && tid == 0) {
            cmp[(size_t)m * 3 + 0] = mx;
            cmp[(size_t)m * 3 + 1] = my;
            cmp[(size_t)m * 3 + 2] = mz;
        }
        float lx = x - mx, ly = y - my, lz = z - mz;
        float n2 = sq3(lx, ly, lz);
#pragma unroll
        for (int msk = 16; msk >= 1; msk >>= 1)
            n2 = fmaxf(n2, __shfl_xor(n2, msk));
        if (tid == 0) atomicMax(scale_bits, __float_as_uint(n2));
    }
}

// ---------------------------------------------------------------- scale
__global__ void finalize_kernel(const unsigned int* scale_bits, float* scale_v) {
    scale_v[0] = sqrtf(__uint_as_float(scale_bits[0]));
}

// ================================================================ MFMA encdec (big-ws path)
// A-frag write helper: element (m=p, k=c) of a [32 x K] A matrix, 16x16x32 tiles
__device__ __forceinline__ int afrag_idx(int p, int c) {
    int ks = c >> 5, mt = p >> 4;
    int lane = (p & 15) + 16 * ((c & 31) >> 3);
    return ((ks * 2 + mt) * 64 + lane) * 8 + (c & 7);
}

template<bool F32>
__global__ __launch_bounds__(256) void encdec_mfma(
        const void* __restrict__ data, const int* __restrict__ selp,
        const float* __restrict__ cmp, const float* __restrict__ scale_p,
        const unsigned int* __restrict__ flagp, const void* __restrict__ gridw,
        const void* __restrict__ We1, const void* __restrict__ be1,
        const unsigned short* __restrict__ We2_sw, const void* __restrict__ be2,
        const void* __restrict__ Wf1a, const unsigned int* __restrict__ p1,
        const void* __restrict__ bf1a,
        const unsigned short* __restrict__ Wf1b_sw, const void* __restrict__ bf1b,
        const void* __restrict__ Wf1c, const void* __restrict__ bf1c,
        const void* __restrict__ Wf2a, const unsigned int* __restrict__ p2,
        const void* __restrict__ bf2a,
        const unsigned short* __restrict__ Wf2b_sw, const void* __restrict__ bf2b,
        const void* __restrict__ Wf2c, const void* __restrict__ bf2c,
        void* __restrict__ out) {
    __shared__ unsigned short afrag[8192];   // 16 KB A-fragments (bf16)
    __shared__ float g2s[32 * 132];          // 16.9 KB [p][j] (+pad)
    __shared__ float code[256];
    __shared__ float xb[96];
    __shared__ float fb[96];
    __shared__ float gridb[64];
    if ((flagp[0] != 0u) != F32) return;
    const int m = blockIdx.x, b = m >> 8, tid = threadIdx.x;
    const int wv = tid >> 6, lane = tid & 63;
    const float scale = scale_p[0];
    const size_t base = (size_t)b * 3 * NN;
    if (tid < 64) gridb[tid] = LD<F32>(gridw, tid);
    if (tid < 32) {
        const int g = selp[(size_t)m * 32 + tid];
        xb[tid * 3 + 0] = (LD<F32>(data, base + g)          - cmp[(size_t)m * 3 + 0]) / scale;
        xb[tid * 3 + 1] = (LD<F32>(data, base + NN + g)     - cmp[(size_t)m * 3 + 1]) / scale;
        xb[tid * 3 + 2] = (LD<F32>(data, base + 2 * NN + g) - cmp[(size_t)m * 3 + 2]) / scale;
    }
    __syncthreads();
    // ---- E2: h1 = relu(x@We1+be1) -> afrag (A of [32p x 128k]) ----
    for (int o = tid; o < 4096; o += 256) {
        int p = o >> 7, ch = o & 127;
        float v = xb[p * 3 + 0] * LD<F32>(We1, ch) + xb[p * 3 + 1] * LD<F32>(We1, 128 + ch)
                + xb[p * 3 + 2] * LD<F32>(We1, 256 + ch) + LD<F32>(be1, ch);
        afrag[afrag_idx(p, ch)] = f2b(fmaxf(v, 0.0f));
    }
    __syncthreads();
    // ---- E3: code = relu(max_p(h1@We2) + be2) via MFMA ----
    {
        f32x4 acc[2][4];
#pragma unroll
        for (int a = 0; a < 2; a++)
#pragma unroll
            for (int t = 0; t < 4; t++) acc[a][t] = (f32x4){0.f, 0.f, 0.f, 0.f};
#pragma unroll
        for (int ks = 0; ks < 4; ks++) {
            short8 a0 = *(const short8*)&afrag[((ks * 2 + 0) * 64 + lane) * 8];
            short8 a1 = *(const short8*)&afrag[((ks * 2 + 1) * 64 + lane) * 8];
#pragma unroll
            for (int nt = 0; nt < 4; nt++) {
                short8 bf = *(const short8*)&We2_sw[((size_t)((4 * wv + nt) * 4 + ks) * 64 + lane) * 8];
                acc[0][nt] = __builtin_amdgcn_mfma_f32_16x16x32_bf16(a0, bf, acc[0][nt], 0, 0, 0);
                acc[1][nt] = __builtin_amdgcn_mfma_f32_16x16x32_bf16(a1, bf, acc[1][nt], 0, 0, 0);
            }
        }
#pragma unroll
        for (int nt = 0; nt < 4; nt++) {
            float mx = acc[0][nt][0];
#pragma unroll
            for (int r = 1; r < 4; r++) mx = fmaxf(mx, acc[0][nt][r]);
#pragma unroll
            for (int r = 0; r < 4; r++) mx = fmaxf(mx, acc[1][nt][r]);
            mx = fmaxf(mx, __shfl_xor(mx, 16));
            mx = fmaxf(mx, __shfl_xor(mx, 32));
            int n = 64 * wv + nt * 16 + (lane & 15);
            if (lane < 16) code[n] = fmaxf(mx + LD<F32>(be2, n), 0.0f);
        }
    }
    __syncthreads();
    // ---- D1: g1 = relu(code@Wf1a + bf1a + grid terms) -> afrag ----
    {
        float a0 = 0.f, a1 = 0.f;
#pragma unroll 8
        for (int k2 = 0; k2 < 128; k2++) {
            unsigned u = p1[k2 * 256 + tid];
            a0 = fmaf(code[2 * k2],     b2f((unsigned short)(u & 0xffffu)), a0);
            a1 = fmaf(code[2 * k2 + 1], b2f((unsigned short)(u >> 16)), a1);
        }
        float base1 = a0 + a1 + LD<F32>(bf1a, tid);
        float wu = LD<F32>(Wf1a, 65536 + tid);
        float wvv = LD<F32>(Wf1a, 65792 + tid);
#pragma unroll 8
        for (int p = 0; p < 32; p++) {
            float v = base1 + gridb[2 * p] * wu + gridb[2 * p + 1] * wvv;
            afrag[afrag_idx(p, tid)] = f2b(fmaxf(v, 0.0f));
        }
    }
    __syncthreads();
    // ---- D2: g2 = relu(g1@Wf1b + bf1b) via MFMA -> g2s ----
    {
        f32x4 acc[2][2];
#pragma unroll
        for (int a = 0; a < 2; a++)
#pragma unroll
            for (int t = 0; t < 2; t++) acc[a][t] = (f32x4){0.f, 0.f, 0.f, 0.f};
#pragma unroll
        for (int ks = 0; ks < 8; ks++) {
            short8 a0 = *(const short8*)&afrag[((ks * 2 + 0) * 64 + lane) * 8];
            short8 a1 = *(const short8*)&afrag[((ks * 2 + 1) * 64 + lane) * 8];
#pragma unroll
            for (int nt = 0; nt < 2; nt++) {
                short8 bf = *(const short8*)&Wf1b_sw[((size_t)((2 * wv + nt) * 8 + ks) * 64 + lane) * 8];
                acc[0][nt] = __builtin_amdgcn_mfma_f32_16x16x32_bf16(a0, bf, acc[0][nt], 0, 0, 0);
                acc[1][nt] = __builtin_amdgcn_mfma_f32_16x16x32_bf16(a1, bf, acc[1][nt], 0, 0, 0);
            }
        }
#pragma unroll
        for (int nt = 0; nt < 2; nt++) {
            int n = 32 * wv + nt * 16 + (lane & 15);
            float bb = LD<F32>(bf1b, n);
#pragma unroll
            for (int mt = 0; mt < 2; mt++)
#pragma unroll
                for (int r = 0; r < 4; r++) {
                    int mm = mt * 16 + (lane >> 4) * 4 + r;
                    g2s[mm * 132 + n] = fmaxf(acc[mt][nt][r] + bb, 0.0f);
                }
        }
    }
    __syncthreads();
    // ---- D3: fb = g2@Wf1c + bf1c ----
    if (tid < 96) {
        int p = tid / 3, e = tid % 3;
        float acc = 0.0f;
#pragma unroll 8
        for (int k = 0; k < 128; k++)
            acc = fmaf(g2s[p * 132 + k], LD<F32>(Wf1c, k * 3 + e), acc);
        fb[tid] = acc + LD<F32>(bf1c, e);
    }
    __syncthreads();
    // ---- D4: g1' = relu(code@Wf2a + bf2a + f terms) -> afrag ----
    {
        float a0 = 0.f, a1 = 0.f;
#pragma unroll 8
        for (int k2 = 0; k2 < 128; k2++) {
            unsigned u = p2[k2 * 256 + tid];
            a0 = fmaf(code[2 * k2],     b2f((unsigned short)(u & 0xffffu)), a0);
            a1 = fmaf(code[2 * k2 + 1], b2f((unsigned short)(u >> 16)), a1);
        }
        float base2 = a0 + a1 + LD<F32>(bf2a, tid);
        float w0 = LD<F32>(Wf2a, 65536 + tid);
        float w1 = LD<F32>(Wf2a, 65792 + tid);
        float w2 = LD<F32>(Wf2a, 66048 + tid);
#pragma unroll 8
        for (int p = 0; p < 32; p++) {
            float v = base2 + fb[p * 3] * w0 + fb[p * 3 + 1] * w1 + fb[p * 3 + 2] * w2;
            afrag[afrag_idx(p, tid)] = f2b(fmaxf(v, 0.0f));
        }
    }
    __syncthreads();
    // ---- D5: g2' = relu(g1'@Wf2b + bf2b) via MFMA -> g2s ----
    {
        f32x4 acc[2][2];
#pragma unroll
        for (int a = 0; a < 2; a++)
#pragma unroll
            for (int t = 0; t < 2; t++) acc[a][t] = (f32x4){0.f, 0.f, 0.f, 0.f};
#pragma unroll
        for (int ks = 0; ks < 8; ks++) {
            short8 a0 = *(const short8*)&afrag[((ks * 2 + 0) * 64 + lane) * 8];
            short8 a1 = *(const short8*)&afrag[((ks * 2 + 1) * 64 + lane) * 8];
#pragma unroll
            for (int nt = 0; nt < 2; nt++) {
                short8 bf = *(const short8*)&Wf2b_sw[((size_t)((2 * wv + nt) * 8 + ks) * 64 + lane) * 8];
                acc[0][nt] = __builtin_amdgcn_mfma_f32_16x16x32_bf16(a0, bf, acc[0][nt], 0, 0, 0);
                acc[1][nt] = __builtin_amdgcn_mfma_f32_16x16x32_bf16(a1, bf, acc[1][nt], 0, 0, 0);
            }
        }
#pragma unroll
        for (int nt = 0; nt < 2; nt++) {
            int n = 32 * wv + nt * 16 + (lane & 15);
            float bb = LD<F32>(bf2b, n);
#pragma unroll
            for (int mt = 0; mt < 2; mt++)
#pragma unroll
                for (int r = 0; r < 4; r++) {
                    int mm = mt * 16 + (lane >> 4) * 4 + r;
                    g2s[mm * 132 + n] = fmaxf(acc[mt][nt][r] + bb, 0.0f);
                }
        }
    }
    __syncthreads();
    // ---- D6: out = (g2'@Wf2c + bf2c)*scale + cmean ----
    if (tid < 96) {
        int p = tid / 3, e = tid % 3;
        float acc = 0.0f;
#pragma unroll 8
        for (int k = 0; k < 128; k++)
            acc = fmaf(g2s[p * 132 + k], LD<F32>(Wf2c, k * 3 + e), acc);
        float v = (acc + LD<F32>(bf2c, e)) * scale + cmp[(size_t)m * 3 + e];
        size_t oi = (size_t)m * 96 + tid;
        if (F32) ((float*)out)[oi] = v;
        else     ((unsigned short*)out)[oi] = f2b(v);
    }
}

// ================================================================ fallback fused encdec (R4)
template<bool F32>
__global__ __launch_bounds__(256) void encdec_fused(
        const void* __restrict__ data,
        const int* __restrict__ perm, const float* __restrict__ centers,
        const float* __restrict__ scale_p, const unsigned int* __restrict__ flagp,
        const void* __restrict__ gridw,
        const void* __restrict__ We1, const void* __restrict__ be1,
        const void* __restrict__ We2, const void* __restrict__ be2,
        const void* __restrict__ Wf1a, const void* __restrict__ bf1a,
        const void* __restrict__ Wf1b, const void* __restrict__ bf1b,
        const void* __restrict__ Wf1c, const void* __restrict__ bf1c,
        const void* __restrict__ Wf2a, const void* __restrict__ bf2a,
        const void* __restrict__ Wf2b, const void* __restrict__ bf2b,
        const void* __restrict__ Wf2c, const void* __restrict__ bf2c,
        void* __restrict__ out) {
    __shared__ float bigA[256 * 36];
    __shared__ float bigB[128 * 36];
    __shared__ float code[256];
    __shared__ float xb[96];
    __shared__ float fb[96];
    __shared__ float gridb[64];
    __shared__ float meansh[4];
    __shared__ float rv4[4];
    __shared__ int   ri4[4];
    __shared__ int   winbuf;
    __shared__ int   sel[NP];
    if ((flagp[0] != 0u) != F32) return;
    const int m = (NB * NC - 1) - blockIdx.x;
    const int b = m >> 8, c = m & 255, tid = threadIdx.x;
    const float scale = scale_p[0];
    const int ci = perm[c];
    const float cx = centers[((size_t)b * NC + ci) * 3 + 0];
    const float cy = centers[((size_t)b * NC + ci) * 3 + 1];
    const float cz = centers[((size_t)b * NC + ci) * 3 + 2];
    const float cn2 = sq3(cx, cy, cz);
    const size_t base = (size_t)b * 3 * NN;
    if (tid < 64) gridb[tid] = LD<F32>(gridw, tid);
    float* dist = bigA;
    float bv = MYFLT_MAX; int bn = tid;
#pragma unroll 4
    for (int j = 0; j < 32; j++) {
        int n = tid + 256 * j;
        float x = LD<F32>(data, base + n);
        float y = LD<F32>(data, base + NN + n);
        float z = LD<F32>(data, base + 2 * NN + n);
        float pn2 = sq3(x, y, z);
        float dot = __fadd_rn(__fadd_rn(__fmul_rn(cx, x), __fmul_rn(cy, y)), __fmul_rn(cz, z));
        float d = __fsub_rn(__fadd_rn(cn2, pn2), __fmul_rn(2.0f, dot));
        dist[n] = d;
        if (d < bv) { bv = d; bn = n; }
    }
    for (int r = 0; r < NP; r++) {
        float v = bv; int n = bn;
#pragma unroll
        for (int off = 32; off >= 1; off >>= 1) {
            float ov = __shfl_down(v, off);
            int   on = __shfl_down(n, off);
            if (ov < v || (ov == v && on < n)) { v = ov; n = on; }
        }
        if ((tid & 63) == 0) { rv4[tid >> 6] = v; ri4[tid >> 6] = n; }
        __syncthreads();
        if (tid == 0) {
            float cv = rv4[0]; int cn = ri4[0];
#pragma unroll
            for (int w = 1; w < 4; w++)
                if (rv4[w] < cv || (rv4[w] == cv && ri4[w] < cn)) { cv = rv4[w]; cn = ri4[w]; }
            if ((unsigned)cn >= NN) cn = 0;
            winbuf = cn; sel[r] = cn;
        }
        __syncthreads();
        const int g = winbuf;
        if ((g & 255) == tid) {
            dist[g] = MYFLT_MAX;
            bv = MYFLT_MAX; bn = tid;
#pragma unroll 4
            for (int j = 0; j < 32; j++) {
                int nn2 = tid + 256 * j;
                float v2 = dist[nn2];
                if (v2 < bv) { bv = v2; bn = nn2; }
            }
        }
    }
    __syncthreads();
    if (tid < 32) {
        const int g = sel[tid];
        float x = LD<F32>(data, base + g);
        float y = LD<F32>(data, base + NN + g);
        float z = LD<F32>(data, base + 2 * NN + g);
        float sx = x, sy = y, sz = z;
#pragma unroll
        for (int msk = 16; msk >= 1; msk >>= 1) {
            sx += __shfl_xor(sx, msk);
            sy += __shfl_xor(sy, msk);
            sz += __shfl_xor(sz, msk);
        }
        float mx = sx / 32.0f, my = sy / 32.0f, mz = sz / 32.0f;
        xb[tid * 3 + 0] = (x - mx) / scale;
        xb[tid * 3 + 1] = (y - my) / scale;
        xb[tid * 3 + 2] = (z - mz) / scale;
        if (tid == 0) { meansh[0] = mx; meansh[1] = my; meansh[2] = mz; }
    }
    __syncthreads();
    for (int o = tid; o < 4096; o += 256) {
        int p = o >> 7, i = o & 127;
        float v = xb[p * 3 + 0] * LD<F32>(We1, i) + xb[p * 3 + 1] * LD<F32>(We1, 128 + i)
                + xb[p * 3 + 2] * LD<F32>(We1, 256 + i) + LD<F32>(be1, i);
        bigB[i * 36 + p] = fmaxf(v, 0.0f);
    }
    __syncthreads();
    {
        float acc[32];
#pragma unroll
        for (int p = 0; p < 32; p++) acc[p] = 0.0f;
        for (int k = 0; k < 128; k++) {
            float w = LD<F32>(We2, k * 256 + tid);
            const float4* hp = (const float4*)&bigB[k * 36];
#pragma unroll
            for (int q = 0; q < 8; q++) {
                float4 h4 = hp[q];
                acc[q * 4 + 0] = fmaf(h4.x, w, acc[q * 4 + 0]);
                acc[q * 4 + 1] = fmaf(h4.y, w, acc[q * 4 + 1]);
                acc[q * 4 + 2] = fmaf(h4.z, w, acc[q * 4 + 2]);
                acc[q * 4 + 3] = fmaf(h4.w, w, acc[q * 4 + 3]);
            }
        }
        float mx = acc[0];
#pragma unroll
        for (int p = 1; p < 32; p++) mx = fmaxf(mx, acc[p]);
        code[tid] = fmaxf(mx + LD<F32>(be2, tid), 0.0f);
    }
    __syncthreads();
    {
        float a0 = 0.f, a1 = 0.f, a2 = 0.f, a3 = 0.f;
        for (int k = 0; k < 256; k += 4) {
            a0 = fmaf(code[k + 0], LD<F32>(Wf1a, (k + 0) * 256 + tid), a0);
            a1 = fmaf(code[k + 1], LD<F32>(Wf1a, (k + 1) * 256 + tid), a1);
            a2 = fmaf(code[k + 2], LD<F32>(Wf1a, (k + 2) * 256 + tid), a2);
            a3 = fmaf(code[k + 3], LD<F32>(Wf1a, (k + 3) * 256 + tid), a3);
        }
        float base1 = ((a0 + a1) + (a2 + a3)) + LD<F32>(bf1a, tid);
        float wu = LD<F32>(Wf1a, 65536 + tid);
        float wvv = LD<F32>(Wf1a, 65792 + tid);
#pragma unroll 8
        for (int p = 0; p < 32; p++) {
            float v = base1 + gridb[2 * p] * wu + gridb[2 * p + 1] * wvv;
            bigA[tid * 36 + p] = fmaxf(v, 0.0f);
        }
    }
    __syncthreads();
    {
        int j = tid & 127, ph = tid >> 7;
        float acc[16];
#pragma unroll
        for (int q = 0; q < 16; q++) acc[q] = 0.0f;
        for (int k = 0; k < 256; k++) {
            float w = LD<F32>(Wf1b, k * 128 + j);
            const float4* gp = (const float4*)&bigA[k * 36 + ph * 16];
            float4 h0 = gp[0], h1 = gp[1], h2 = gp[2], h3 = gp[3];
            acc[0] = fmaf(h0.x, w, acc[0]);   acc[1] = fmaf(h0.y, w, acc[1]);
            acc[2] = fmaf(h0.z, w, acc[2]);   acc[3] = fmaf(h0.w, w, acc[3]);
            acc[4] = fmaf(h1.x, w, acc[4]);   acc[5] = fmaf(h1.y, w, acc[5]);
            acc[6] = fmaf(h1.z, w, acc[6]);   acc[7] = fmaf(h1.w, w, acc[7]);
            acc[8] = fmaf(h2.x, w, acc[8]);   acc[9] = fmaf(h2.y, w, acc[9]);
            acc[10] = fmaf(h2.z, w, acc[10]); acc[11] = fmaf(h2.w, w, acc[11]);
            acc[12] = fmaf(h3.x, w, acc[12]); acc[13] = fmaf(h3.y, w, acc[13]);
            acc[14] = fmaf(h3.z, w, acc[14]); acc[15] = fmaf(h3.w, w, acc[15]);
        }
        float bb = LD<F32>(bf1b, j);
#pragma unroll
        for (int q = 0; q < 16; q++)
            bigB[j * 36 + ph * 16 + q] = fmaxf(acc[q] + bb, 0.0f);
    }
    __syncthreads();
    if (tid < 96) {
        int p = tid / 3, e = tid % 3;
        float acc = 0.0f;
        for (int k = 0; k < 128; k++)
            acc = fmaf(bigB[k * 36 + p], LD<F32>(Wf1c, k * 3 + e), acc);
        fb[tid] = acc + LD<F32>(bf1c, e);
    }
    __syncthreads();
    {
        float a0 = 0.f, a1 = 0.f, a2 = 0.f, a3 = 0.f;
        for (int k = 0; k < 256; k += 4) {
            a0 = fmaf(code[k + 0], LD<F32>(Wf2a, (k + 0) * 256 + tid), a0);
            a1 = fmaf(code[k + 1], LD<F32>(Wf2a, (k + 1) * 256 + tid), a1);
            a2 = fmaf(code[k + 2], LD<F32>(Wf2a, (k + 2) * 256 + tid), a2);
            a3 = fmaf(code[k + 3], LD<F32>(Wf2a, (k + 3) * 256 + tid), a3);
        }
        float base2 = ((a0 + a1) + (a2 + a3)) + LD<F32>(bf2a, tid);
        float w0 = LD<F32>(Wf2a, 65536 + tid);
        float w1 = LD<F32>(Wf2a, 65792 + tid);
        float w2 = LD<F32>(Wf2a, 66048 + tid);
#pragma unroll 8
        for (int p = 0; p < 32; p++) {
            float v = base2 + fb[p * 3] * w0 + fb[p * 3 + 1] * w1 + fb[p * 3 + 2] * w2;
            bigA[tid * 36 + p] = fmaxf(v, 0.0f);
        }
    }
    __syncthreads();
    {
        int j = tid & 127, ph = tid >> 7;
        float acc[16];
#pragma unroll
        for (int q = 0; q < 16; q++) acc[q] = 0.0f;
        for (int k = 0; k < 256; k++) {
            float w = LD<F32>(Wf2b, k * 128 + j);
            const float4* gp = (const float4*)&bigA[k * 36 + ph * 16];
            float4 h0 = gp[0], h1 = gp[1], h2 = gp[2], h3 = gp[3];
            acc[0] = fmaf(h0.x, w, acc[0]);   acc[1] = fmaf(h0.y, w, acc[1]);
            acc[2] = fmaf(h0.z, w, acc[2]);   acc[3] = fmaf(h0.w, w, acc[3]);
            acc[4] = fmaf(h1.x, w, acc[4]);   acc[5] = fmaf(h1.y, w, acc[5]);
            acc[6] = fmaf(h1.z, w, acc[6]);   acc[7] = fmaf(h1.w, w, acc[7]);
            acc[8] = fmaf(h2.x, w, acc[8]);   acc[9] = fmaf(h2.y, w, acc[9]);
            acc[10] = fmaf(h2.z, w, acc[10]); acc[11] = fmaf(h2.w, w, acc[11]);
            acc[12] = fmaf(h3.x, w, acc[12]); acc[13] = fmaf(h3.y, w, acc[13]);
            acc[14] = fmaf(h3.z, w, acc[14]); acc[15] = fmaf(h3.w, w, acc[15]);
        }
        float bb = LD<F32>(bf2b, j);
#pragma unroll
        for (int q = 0; q < 16; q++)
            bigB[j * 36 + ph * 16 + q] = fmaxf(acc[q] + bb, 0.0f);
    }
    __syncthreads();
    if (tid < 96) {
        int p = tid / 3, e = tid % 3;
        float acc = 0.0f;
        for (int k = 0; k < 128; k++)
            acc = fmaf(bigB[k * 36 + p], LD<F32>(Wf2c, k * 3 + e), acc);
        float v = (acc + LD<F32>(bf2c, e)) * scale + meansh[e];
        size_t oi = (size_t)m * 96 + tid;
        if (F32) ((float*)out)[oi] = v;
        else     ((unsigned short*)out)[oi] = f2b(v);
    }
}

extern "C" void kernel_launch(void* const* d_in, const int* in_sizes, int n_in,
                              void* d_out, int out_size, void* d_ws, size_t ws_size,
                              hipStream_t stream) {
    const void* data = d_in[0];
    const int* perm  = (const int*)d_in[1];
    const void* grid = d_in[2];
    const void *We1 = d_in[3], *be1 = d_in[4], *We2 = d_in[5], *be2 = d_in[6];
    const void *Wf1a = d_in[7], *bf1a = d_in[8], *Wf1b = d_in[9], *bf1b = d_in[10];
    const void *Wf1c = d_in[11], *bf1c = d_in[12];
    const void *Wf2a = d_in[13], *bf2a = d_in[14], *Wf2b = d_in[15], *bf2b = d_in[16];
    const void *Wf2c = d_in[17], *bf2c = d_in[18];

    if (ws_size >= (size_t)4 * 1024 * 1024) {
        // ---------- big-ws MFMA path ----------
        float* ws = (float*)d_ws;
        unsigned int* wbase   = (unsigned int*)ws;     // [0]=scale_bits,[2]=flag
        float*        scale_v = ws + 1;
        unsigned int* flagp   = wbase + 2;
        float*        centers = ws + 4;                // 24576
        float*        cmeanp  = ws + 24580;            // 24576
        int*          selp    = (int*)(ws + 49156);    // 262144
        unsigned short* We2_sw  = (unsigned short*)(ws + 311304);  // 32768 bf16
        unsigned short* Wf1b_sw = (unsigned short*)(ws + 327688);
        unsigned short* Wf2b_sw = (unsigned short*)(ws + 344072);
        unsigned int*   p1      = (unsigned int*)(ws + 360456);    // 32768 u32
        unsigned int*   p2      = (unsigned int*)(ws + 393224);

        init_kernel<<<1, 1, 0, stream>>>(wbase);
        detect_kernel<<<256, 256, 0, stream>>>(data, flagp);
        prep_kernel<false><<<640, 256, 0, stream>>>(We2, Wf1b, Wf2b, Wf1a, Wf2a, flagp,
                                                    We2_sw, Wf1b_sw, Wf2b_sw, p1, p2);
        prep_kernel<true ><<<640, 256, 0, stream>>>(We2, Wf1b, Wf2b, Wf1a, Wf2a, flagp,
                                                    We2_sw, Wf1b_sw, Wf2b_sw, p1, p2);
        fps_kernel<false><<<NB, 1024, 0, stream>>>(data, flagp, centers);
        fps_kernel<true ><<<NB, 1024, 0, stream>>>(data, flagp, centers);
        knn_kernel<false><<<NB * NC, 256, 0, stream>>>(data, perm, centers, flagp, wbase, selp, cmeanp);
        knn_kernel<true ><<<NB * NC, 256, 0, stream>>>(data, perm, centers, flagp, wbase, selp, cmeanp);
        finalize_kernel<<<1, 1, 0, stream>>>(wbase, scale_v);
        encdec_mfma<false><<<NB * NC, 256, 0, stream>>>(data, selp, cmeanp, scale_v, flagp, grid,
                We1, be1, We2_sw, be2, Wf1a, p1, bf1a, Wf1b_sw, bf1b, Wf1c, bf1c,
                Wf2a, p2, bf2a, Wf2b_sw, bf2b, Wf2c, bf2c, d_out);
        encdec_mfma<true ><<<NB * NC, 256, 0, stream>>>(data, selp, cmeanp, scale_v, flagp, grid,
                We1, be1, We2_sw, be2, Wf1a, p1, bf1a, Wf1b_sw, bf1b, Wf1c, bf1c,
                Wf2a, p2, bf2a, Wf2b_sw, bf2b, Wf2c, bf2c, d_out);
    } else {
        // ---------- fallback: R4 path verbatim ----------
        float* ov = (ws_size >= (size_t)131072) ? (float*)d_ws : (float*)d_out;
        unsigned int* wbase   = (unsigned int*)ov;
        float*        scale_v = ov + 1;
        unsigned int* flagp   = wbase + 2;
        float*        centers = ov + 4;

        init_kernel<<<1, 1, 0, stream>>>(wbase);
        detect_kernel<<<256, 256, 0, stream>>>(data, flagp);
        fps_kernel<false><<<NB, 1024, 0, stream>>>(data, flagp, centers);
        fps_kernel<true ><<<NB, 1024, 0, stream>>>(data, flagp, centers);
        knn_kernel<false><<<NB * NC, 256, 0, stream>>>(data, perm, centers, flagp, wbase, nullptr, nullptr);
        knn_kernel<true ><<<NB * NC, 256, 0, stream>>>(data, perm, centers, flagp, wbase, nullptr, nullptr);
        finalize_kernel<<<1, 1, 0, stream>>>(wbase, scale_v);
        encdec_fused<false><<<NB * NC, 256, 0, stream>>>(data, perm, centers, scale_v, flagp,
                grid, We1, be1, We2, be2, Wf1a, bf1a, Wf1b, bf1b, Wf1c, bf1c,
                Wf2a, bf2a, Wf2b, bf2b, Wf2c, bf2c, d_out);
        encdec_fused<true ><<<NB * NC, 256, 0, stream>>>(data, perm, centers, scale_v, flagp,
                grid, We1, be1, We2, be2, Wf1a, bf1a, Wf1b, bf1b, Wf1c, bf1c,
                Wf2a, bf2a, Wf2b, bf2b, Wf2c, bf2c, d_out);
    }
}